// Round 5
// baseline (918.753 us; speedup 1.0000x reference)
//
#include <hip/hip_runtime.h>

// ---------------------------------------------------------------------------
// Problem constants
// ---------------------------------------------------------------------------
constexpr int CT = 32;      // T
constexpr int CN = 64;      // N
constexpr int CE = 256;     // E = DOBS*V
constexpr int CHID = 1024;
constexpr int CA = 32;      // num options
constexpr int CS = 32;      // planning steps
constexpr int CHP = 8;      // planning horizon
constexpr int TN = CT * CN; // 2048

// d_out float offsets (return order: search_logits, planned_actions, X, value,
// model_loss, embed_loss)
constexpr size_t O_SL  = 0;        // 32*64*32 = 65536
constexpr size_t O_PA  = 65536;    // 64*8     = 512
constexpr size_t O_X   = 66048;    // 64*8*256 = 131072
constexpr size_t O_VAL = 197120;   // 32*64    = 2048
constexpr size_t O_ML  = 199168;   // 32*64*256= 524288
constexpr size_t O_EL  = 723456;   // 32*64    = 2048

// ws byte offsets (~100 MB total)
constexpr size_t B_EMB    = 0;                           // 2 MB   [2048][256] f32
constexpr size_t B_H1     = 2u * 1024 * 1024;            // 256 KB [64][1024]
constexpr size_t B_XS     = B_H1 + 256 * 1024;           // 128 KB [64][512]
constexpr size_t B_PART   = B_XS + 128 * 1024;           // 1 MB   [2 par][64][8][256]
// control block at 3.5 MB
constexpr size_t B_CNT    = 3584u * 1024;                // 32*32 ints
constexpr size_t B_DEC    = B_CNT + 8 * 1024;            // 32 ints
constexpr size_t B_ROW    = B_DEC + 4 * 1024;            // 32*64 ints
constexpr size_t B_LISTS  = B_ROW + 16 * 1024;           // 32*32*64 ints = 256 KB
constexpr size_t B_CNTTL  = B_LISTS + 272 * 1024;        // 32 ints
constexpr size_t B_LISTTL = B_CNTTL + 4 * 1024;          // 32 KB [32][256]
// 32MB+ multi-phase region: We2T (early) -> Wm1T (mid) -> xstl/hbig/parttl/Wm2T
constexpr size_t B_R32    = 4u * 1024 * 1024;
constexpr size_t B_WE2T   = B_R32;                       // 1 MB  (dead after x0)
constexpr size_t B_WM1T   = B_R32;                       // 32 MB (dead after wpm)
constexpr size_t B_XSTL   = B_R32;                       // 4 MB  [2048][512]
constexpr size_t B_HBIG   = B_R32 + 4u * 1024 * 1024;    // 8 MB  [2048][1024]
constexpr size_t B_PARTTL = B_R32 + 12u * 1024 * 1024;   // 16 MB [2048][8][256]
constexpr size_t B_WM2T   = B_R32 + 28u * 1024 * 1024;   // 1 MB  [1024][256]
constexpr size_t B_WPM    = B_R32 + 32u * 1024 * 1024;   // 64 MB [32][512][1024]

// LDS scalar-state indices for fin blocks
constexpr int SI_FLAG = 0, SI_I = 1, SI_PUSH = 2, SI_IUP = 3;

__device__ __forceinline__ void fma4(float4& a, float s, const float4& w) {
  a.x = fmaf(s, w.x, a.x); a.y = fmaf(s, w.y, a.y);
  a.z = fmaf(s, w.z, a.z); a.w = fmaf(s, w.w, a.w);
}

// ---------------------------------------------------------------------------
// init: zero PA+X span of d_out, per-step counters, flags
// ---------------------------------------------------------------------------
__global__ void init_kernel(float* __restrict__ out, int* __restrict__ cnt,
                            int* __restrict__ dec, int* __restrict__ row,
                            int* __restrict__ cnt_tl) {
  int idx = blockIdx.x * 256 + threadIdx.x;
  if (idx < 131584) out[O_PA + idx] = 0.f;  // PA (512) + X (131072) contiguous
  if (idx < CS * CA) cnt[idx] = 0;
  if (idx < CS) dec[idx] = 0;
  if (idx < CS * CN) row[idx] = 0;
  if (idx < CA) cnt_tl[idx] = 0;
}

// ---------------------------------------------------------------------------
// emb[t][n][e] = embed1[obs[t][n][e>>4]][e&15]
// ---------------------------------------------------------------------------
__global__ void emb_kernel(const int* __restrict__ obs, const float* __restrict__ embed1,
                           float* __restrict__ emb) {
  int idx = blockIdx.x * 256 + threadIdx.x;
  int b = idx >> 5, k8 = idx & 31;
  int e0 = k8 * 8;
  int d = e0 >> 4;
  int o = obs[b * 16 + d];
  const float* src = embed1 + o * 16 + (e0 & 15);
  float4 v0 = *(const float4*)src;
  float4 v1 = *(const float4*)(src + 4);
  float* dst = emb + (size_t)b * CE + e0;
  *(float4*)dst = v0;
  *(float4*)(dst + 4) = v1;
}

// ---------------------------------------------------------------------------
// One GRU step with h0 = 0 (only Hs[0] used downstream; Whh provably unused)
// ---------------------------------------------------------------------------
__global__ void h1_kernel(const float* __restrict__ emb, const float* __restrict__ Wih,
                          const float* __restrict__ bih, const float* __restrict__ bhh,
                          float* __restrict__ h1) {
  int t = threadIdx.x, bid = blockIdx.x;   // 256 blocks of (64n x 4j)
  int n = t & 63, j = bid * 4 + (t >> 6);
  const float* x = emb + (size_t)n * CE;   // emb[0] rows
  const float* wr = Wih + (size_t)j * CE;
  const float* wz = Wih + (size_t)(CHID + j) * CE;
  const float* wn = Wih + (size_t)(2 * CHID + j) * CE;
  float ar = 0.f, az = 0.f, an = 0.f;
  #pragma unroll 4
  for (int e = 0; e < CE; ++e) {
    float xe = x[e];
    ar += xe * wr[e]; az += xe * wz[e]; an += xe * wn[e];
  }
  ar += bih[j] + bhh[j];
  az += bih[CHID + j] + bhh[CHID + j];
  float r = 1.f / (1.f + expf(-ar));
  float z = 1.f / (1.f + expf(-az));
  float nn = tanhf(an + bih[2 * CHID + j] + r * bhh[2 * CHID + j]);
  h1[(size_t)n * CHID + j] = (1.f - z) * nn;
}

// ---------------------------------------------------------------------------
// Generic 64x64 tiled transpose: in[R][C] -> out[C][R]
// ---------------------------------------------------------------------------
__global__ void trans_kernel(const float* __restrict__ in, float* __restrict__ out,
                             int R, int C) {
  __shared__ float tile[64][65];
  int tj = threadIdx.x & 63, tg = threadIdx.x >> 6;
  int cb = blockIdx.x * 64, rb = blockIdx.y * 64;
  #pragma unroll
  for (int i = 0; i < 16; ++i) {
    int r = tg * 16 + i;
    tile[r][tj] = in[(size_t)(rb + r) * C + cb + tj];
  }
  __syncthreads();
  #pragma unroll
  for (int i = 0; i < 16; ++i) {
    int c2 = tg * 16 + i;
    out[(size_t)(cb + c2) * R + rb + tj] = tile[tj][c2];
  }
}

// ---------------------------------------------------------------------------
// X[:,0] = h1 @ We2^T + be2   (We2T layout [k][e])
// ---------------------------------------------------------------------------
__global__ void x0_kernel(const float* __restrict__ h1, const float* __restrict__ We2T,
                          const float* __restrict__ be2, float* __restrict__ Xout) {
  int et = blockIdx.x, n = blockIdx.y, t = threadIdx.x;
  int el = t & 63, kq = t >> 6;
  __shared__ float hr[1024];
  __shared__ float sred2[4][64];
  for (int idx = t; idx < 1024; idx += 256) hr[idx] = h1[(size_t)n * CHID + idx];
  __syncthreads();
  int e = et * 64 + el;
  float acc = 0.f;
  for (int k = kq * 256; k < kq * 256 + 256; ++k) acc += hr[k] * We2T[(size_t)k * CE + e];
  sred2[kq][el] = acc;
  __syncthreads();
  if (t < 64) {
    float s2 = sred2[0][t] + sred2[1][t] + sred2[2][t] + sred2[3][t] + be2[et * 64 + t];
    Xout[(size_t)(n * CHP) * CE + et * 64 + t] = s2;
  }
}

// ---------------------------------------------------------------------------
// Factorized model weights:
// Wpm[o][e][j]     = sum_a relu( embed_opt[o][a]) * Wm1[j][a*256+e]
// Wpm[o][256+e][j] = sum_a relu(-embed_opt[o][a]) * Wm1[j][a*256+e]
// ---------------------------------------------------------------------------
__global__ void wpm_kernel(const float* __restrict__ Wm1T, const float* __restrict__ eo,
                           float* __restrict__ Wpm) {
  int e = blockIdx.x, jt = blockIdx.y, t = threadIdx.x;
  int j = jt * 256 + t;
  __shared__ float rp[CA * CA], rm[CA * CA];
  for (int idx = t; idx < CA * CA; idx += 256) {
    float v = eo[idx];
    rp[idx] = fmaxf(v, 0.f);
    rm[idx] = fmaxf(-v, 0.f);
  }
  __syncthreads();
  float w[32];
  #pragma unroll
  for (int a = 0; a < 32; ++a) w[a] = Wm1T[(size_t)(a * 256 + e) * CHID + j];
  for (int o = 0; o < 32; ++o) {
    float sp = 0.f, sm = 0.f;
    #pragma unroll
    for (int a = 0; a < 32; ++a) {
      float wa = w[a];
      sp += rp[o * 32 + a] * wa;
      sm += rm[o * 32 + a] * wa;
    }
    Wpm[((size_t)o * 512 + e) * CHID + j] = sp;
    Wpm[((size_t)o * 512 + 256 + e) * CHID + j] = sm;
  }
}

// ---------------------------------------------------------------------------
// Group time-loop rows by option (list order nondeterministic; results aren't)
// ---------------------------------------------------------------------------
__global__ void tllists_kernel(const int* __restrict__ P, int* __restrict__ cnt_tl,
                               int* __restrict__ list_tl) {
  int b = blockIdx.x * 256 + threadIdx.x;
  if (b >= TN) return;
  int a = P[b];
  int slot = atomicAdd(&cnt_tl[a], 1);
  list_tl[a * 256 + slot] = b;
}

// xs_tl[b][k] = relu(+/- prev[b][k&255]),  prev = emb shifted by one t (wrap)
__global__ void xstl_kernel(const float* __restrict__ emb, float* __restrict__ xs) {
  int idx = blockIdx.x * 256 + threadIdx.x;   // < 2048*512
  int b = idx >> 9, k = idx & 511;
  int e = k & 255;
  int bp = (b < CN) ? (b + (CT - 1) * CN) : (b - CN);
  float v = emb[(size_t)bp * CE + e];
  xs[idx] = (k < 256) ? fmaxf(v, 0.f) : fmaxf(-v, 0.f);
}

// ---------------------------------------------------------------------------
// Time-loop factorized model layer 1:
// h[row][j] = relu( sum_{k<512} xs[row][k] * Wpm[o][k][j] + bm1[j] )
// grid (32 o, 8 j-tiles of 128, z row-group start)
// ---------------------------------------------------------------------------
__global__ __launch_bounds__(256) void l1_kernel(
    const float* __restrict__ Wpm, const float* __restrict__ xs,
    const float* __restrict__ bm1, const int* __restrict__ cnt,
    const int* __restrict__ list, int listStride, float* __restrict__ hout) {
  int o = blockIdx.x, jt = blockIdx.y;
  int c = cnt[o];
  if (c <= 0) return;
  __shared__ __align__(16) float sbuf[8192];
  __shared__ int srows[8];
  int t = threadIdx.x;
  int jl = t & 31, kq = t >> 5;
  int jb = jt * 128;
  const float* wb = Wpm + (size_t)o * (512 * CHID) + jb + jl * 4;
  for (int g = blockIdx.z; g * 8 < c; g += gridDim.z) {
    int base = g * 8;
    int nr = min(8, c - base);
    if (t < 8) srows[t] = (t < nr) ? list[o * listStride + base + t] : -1;
    __syncthreads();
    for (int idx = t; idx < 4096; idx += 256) {
      int row = srows[idx >> 9];
      sbuf[idx] = (row >= 0) ? xs[(size_t)row * 512 + (idx & 511)] : 0.f;
    }
    __syncthreads();
    float4 acc[8];
    #pragma unroll
    for (int r = 0; r < 8; ++r) acc[r] = make_float4(0.f, 0.f, 0.f, 0.f);
    int kbase = kq * 64;
    for (int k4 = 0; k4 < 64; k4 += 4) {
      int k = kbase + k4;
      float4 w0 = *(const float4*)(wb + (size_t)(k + 0) * CHID);
      float4 w1 = *(const float4*)(wb + (size_t)(k + 1) * CHID);
      float4 w2 = *(const float4*)(wb + (size_t)(k + 2) * CHID);
      float4 w3 = *(const float4*)(wb + (size_t)(k + 3) * CHID);
      #pragma unroll
      for (int r = 0; r < 8; ++r) {
        float4 xv = *(const float4*)&sbuf[r * 512 + k];
        fma4(acc[r], xv.x, w0); fma4(acc[r], xv.y, w1);
        fma4(acc[r], xv.z, w2); fma4(acc[r], xv.w, w3);
      }
    }
    __syncthreads();
    #pragma unroll
    for (int r = 0; r < 8; ++r)
      *(float4*)&sbuf[(kq * 8 + r) * 128 + jl * 4] = acc[r];
    __syncthreads();
    for (int idx = t; idx < 1024; idx += 256) {
      int r = idx >> 7, jc = idx & 127;
      float s = 0.f;
      #pragma unroll
      for (int q = 0; q < 8; ++q) s += sbuf[(q * 8 + r) * 128 + jc];
      int row = srows[r];
      if (row >= 0)
        hout[(size_t)row * CHID + jb + jc] = fmaxf(s + bm1[jb + jc], 0.f);
    }
    __syncthreads();
  }
}

// ---------------------------------------------------------------------------
// Time-loop layer 2 partials: part[b][kq][e], 8 k-slices of 128
// grid (8 kq, 64 row-groups of 32), 256 thr (= e)
// ---------------------------------------------------------------------------
__global__ __launch_bounds__(256) void l2big_kernel(const float* __restrict__ h,
    const float* __restrict__ Wm2T, float* __restrict__ part) {
  int kq = blockIdx.x, rg = blockIdx.y, t = threadIdx.x;
  int rb = rg * 32, kb = kq * 128;
  __shared__ __align__(16) float hl[4096];
  for (int idx = t; idx < 4096; idx += 256)
    hl[idx] = h[(size_t)(rb + (idx >> 7)) * CHID + kb + (idx & 127)];
  __syncthreads();
  float acc[32];
  #pragma unroll
  for (int r = 0; r < 32; ++r) acc[r] = 0.f;
  for (int kk = 0; kk < 128; kk += 4) {
    float w0 = Wm2T[(size_t)(kb + kk + 0) * CE + t];
    float w1 = Wm2T[(size_t)(kb + kk + 1) * CE + t];
    float w2 = Wm2T[(size_t)(kb + kk + 2) * CE + t];
    float w3 = Wm2T[(size_t)(kb + kk + 3) * CE + t];
    #pragma unroll
    for (int r = 0; r < 32; ++r) {
      float4 hv = *(const float4*)&hl[r * 128 + kk];
      acc[r] += hv.x * w0 + hv.y * w1 + hv.z * w2 + hv.w * w3;
    }
  }
  #pragma unroll
  for (int r = 0; r < 32; ++r)
    part[((size_t)(rb + r) * 8 + kq) * CE + t] = acc[r];
}

// model_loss = (sum(partials)+bm2 - emb)^2
__global__ void ml_kernel(const float* __restrict__ part, const float* __restrict__ bm2,
                          const float* __restrict__ emb, float* __restrict__ ML) {
  int idx = blockIdx.x * 256 + threadIdx.x;   // < 2048*256
  int b = idx >> 8, e = idx & 255;
  float outv = bm2[e];
  #pragma unroll
  for (int q = 0; q < 8; ++q) outv += part[((size_t)b * 8 + q) * CE + e];
  float d = outv - emb[idx];
  ML[idx] = d * d;
}

// ---------------------------------------------------------------------------
// fin phase (blocks 0..63, n = bid): epilogue of step s-1 + decision of step s.
// Per-n state (I, push, Iup, logits, X copy) lives in block LDS. Cross-block:
// spin row_done[s-1][n]==8 (only if pushed), part_db reads, xs/cnt/lists
// writes, release-fence + dec_done[s] arrive. s==CS: epilogue only.
// NOTE: no Wc register prefetch — keeps pressure low so plan_kernel's 32
// named weight float4s stay register-resident (round-3/4 spill bug).
// ---------------------------------------------------------------------------
__device__ __forceinline__ void fin_phase(
    int s, int n, int t,
    const int* __restrict__ P, const float* __restrict__ Wsg,
    const float* __restrict__ bsg, const float* __restrict__ Wcg,
    const float* __restrict__ bcg, const float* __restrict__ bm2,
    const float* __restrict__ part_db, float* __restrict__ Xout,
    float* __restrict__ SLout, float* __restrict__ VALout,
    float* __restrict__ PAout, float* __restrict__ xsbuf,
    int* __restrict__ cnt, int* __restrict__ lists,
    int* __restrict__ row_done, int* __restrict__ dec_done,
    float* sx, float* sred, float* svals, float* sxtra, int* sint,
    float* logits_s, float* Xlds) {
  float wsv = 0.f, bm2v = 0.f, bcv = 0.f, bsv = bsg[0];
  int c2 = t >> 3, g = t & 7;
  if (t < 256) { wsv = Wsg[t]; bm2v = bm2[t]; }
  if (t < CA) bcv = bcg[t];

  if (s > 0) {
    int push = sint[SI_PUSH];
    if (push) {
      if (t == 0) {
        int* rd = &row_done[(s - 1) * CN + n];
        while (__hip_atomic_load(rd, __ATOMIC_RELAXED, __HIP_MEMORY_SCOPE_AGENT) < 8)
          __builtin_amdgcn_s_sleep(1);
        __builtin_amdgcn_fence(__ATOMIC_ACQUIRE, "agent");
      }
      __syncthreads();
      int Iup = sint[SI_IUP];
      if (t < 256) {
        const float* pb = part_db + (((size_t)((s - 1) & 1) * CN + n) * 8) * CE + t;
        float outv = bm2v;
        #pragma unroll
        for (int q = 0; q < 8; ++q) outv += pb[(size_t)q * CE];
        Xlds[Iup * CE + t] = outv;
        Xout[((size_t)(n * CHP) + Iup) * CE + t] = outv;
        sx[t] = outv;
      }
      if (t == 0) sint[SI_I] = Iup;
    } else {
      int I = sint[SI_I];
      int Inew = (I - 1 > 0) ? I - 1 : 0;
      if (t < 256) sx[t] = Xlds[Inew * CE + t];
      if (t == 0) sint[SI_I] = Inew;
    }
    if (s == CS) return;  // final epilogue only (uniform)
  } else {
    if (t < 256) sx[t] = Xlds[t];
    if (t == 0) sint[SI_I] = 0;
  }
  __syncthreads();
  int I = sint[SI_I];
  if (t < 256) {
    float xv = sx[t];
    float xa = fmaxf(xv, 0.f);
    xsbuf[n * 512 + t] = xa;
    xsbuf[n * 512 + 256 + t] = fmaxf(-xv, 0.f);
    sred[t] = xa * wsv;
  }
  __syncthreads();
  #pragma unroll
  for (int off = 128; off > 0; off >>= 1) {
    if (t < off) sred[t] += sred[t + off];
    __syncthreads();
  }
  if (t == 0) { sxtra[0] = sred[0] + bsv; sint[SI_FLAG] = 1; }
  if (t < 256) {
    float pv = 0.f;
    const float* wrow = Wcg + c2 * CE + g * 32;
    #pragma unroll 4
    for (int i = 0; i < 32; ++i)
      pv += fmaxf(sx[g * 32 + i], 0.f) * wrow[i];
    pv += __shfl_down(pv, 4, 8);
    pv += __shfl_down(pv, 2, 8);
    pv += __shfl_down(pv, 1, 8);
    if (g == 0) svals[c2] = pv + bcv;
  }
  __syncthreads();
  if (t < CA && logits_s[t] != 0.f) sint[SI_FLAG] = 0;
  __syncthreads();
  int a = P[s * CN + n];
  if (t < CA) {
    float v = svals[t];
    float slv = sint[SI_FLAG] ? sxtra[0] * v : logits_s[t];
    SLout[(size_t)(s * CN + n) * CA + t] = slv;
    logits_s[t] = slv - (t == a ? 1e8f : 0.f);
    if (t == a) {
      VALout[s * CN + n] = slv;
      int pn = (v > 0.f) ? 1 : 0;
      sint[SI_PUSH] = pn;
      PAout[n * CHP + I] = (float)a;
      sint[SI_IUP] = (I + 1 < CHP - 1) ? I + 1 : CHP - 1;
      if (pn) {
        int slot = atomicAdd(&cnt[s * CA + a], 1);
        lists[(s * CA + a) * CN + slot] = n;
      }
    }
  }
  __syncthreads();
  if (t == 0) {
    __builtin_amdgcn_fence(__ATOMIC_RELEASE, "agent");   // flush xs/lists/outputs
    __hip_atomic_fetch_add(&dec_done[s], 1, __ATOMIC_RELAXED, __HIP_MEMORY_SCOPE_AGENT);
  }
  __syncthreads();
}

// ---------------------------------------------------------------------------
// Persistent planning kernel: 256 blocks x 512 threads (1 block/CU, LDS-forced).
// Block (o,jt): Wpm[o][:, jb..jb+128) in 32 NAMED float4 registers per thread.
// __launch_bounds__(512, 1): weakest waves/EU constraint -> 256 VGPR cap, so
// the 128 weight VGPRs fit ((512,2) imposed a 128 cap and spilled them —
// rounds 3/4 bug, VGPR_Count 124/128 observed).
// No global barrier: dec_done / row_done producer-consumer counters.
// ---------------------------------------------------------------------------
#define W_EACH(M) M(0) M(1) M(2) M(3) M(4) M(5) M(6) M(7) M(8) M(9) M(10) \
  M(11) M(12) M(13) M(14) M(15) M(16) M(17) M(18) M(19) M(20) M(21) M(22) \
  M(23) M(24) M(25) M(26) M(27) M(28) M(29) M(30) M(31)
#define WLD(i) float4 W##i = *(const float4*)(wsrc + (size_t)(i) * CHID);
#define WFM(i) { float xv_ = xk[i]; \
  acc.x = fmaf(xv_, W##i.x, acc.x); acc.y = fmaf(xv_, W##i.y, acc.y); \
  acc.z = fmaf(xv_, W##i.z, acc.z); acc.w = fmaf(xv_, W##i.w, acc.w); }

__global__ __launch_bounds__(512, 1) void plan_kernel(
    const float* __restrict__ Wpm, const float* __restrict__ Wm2T,
    const float* __restrict__ bm1g, const int* __restrict__ P,
    const float* Wsg, const float* bsg, const float* Wcg, const float* bcg,
    const float* bm2, float* Xout, float* SLout, float* VALout, float* PAout,
    float* xsbuf, int* cnt, int* lists, int* row_done, int* dec_done,
    float* part_db) {
  extern __shared__ float smem[];
  float* wm2s    = smem;                  // [256 e][130 pad] = 33280
  float* bm1s    = wm2s + 33280;          // 128
  float* red     = bm1s + 128;            // 16*128 = 2048
  float* sh      = red + 2048;            // 128
  float* sxs     = sh + 128;              // 4*512 = 2048
  float* sx      = sxs + 2048;            // 256
  float* sred    = sx + 256;              // 256
  float* svals   = sred + 256;            // 32
  float* sxtra   = svals + 32;            // 4
  int*   sint    = (int*)(sxtra + 4);     // 8
  int*   srows   = sint + 8;              // 4
  int*   rowsAll = srows + 4;             // 64
  float* logits_s= (float*)(rowsAll + 64);// 32
  float* Xlds    = logits_s + 32;         // 2048
  // total 40336 floats = 161344 B <= 160 KiB

  int bid = blockIdx.x, t = threadIdx.x;
  int o = bid >> 3, jt = bid & 7;
  int jl = t & 31, kq = t >> 5;           // kq in [0,16): 32 k each
  int jb = jt * 128;

  // --- prologue: weights resident in NAMED registers + LDS ---
  const float* wsrc = Wpm + ((size_t)o * 512 + (size_t)kq * 32) * CHID + jb + jl * 4;
  W_EACH(WLD)
  for (int idx = t; idx < 128 * 256; idx += 512) {
    int e = idx & 255, j = idx >> 8;
    wm2s[e * 130 + j] = Wm2T[(size_t)(jb + j) * CE + e];
  }
  if (t < 128) bm1s[t] = bm1g[jb + t];
  if (bid < CN) {
    for (int idx = t; idx < CHP * CE; idx += 512)
      Xlds[idx] = Xout[(size_t)bid * (CHP * CE) + idx];
    if (t < 32) logits_s[t] = 0.f;
    if (t < 8) sint[t] = 0;
  }
  __syncthreads();

  if (bid < CN)
    fin_phase(0, bid, t, P, Wsg, bsg, Wcg, bcg, bm2, part_db, Xout, SLout,
              VALout, PAout, xsbuf, cnt, lists, row_done, dec_done,
              sx, sred, svals, sxtra, sint, logits_s, Xlds);

  for (int s = 0; s < CS; ++s) {
    // --- phase A: wait decisions, run l1+l2 for this option's pushed rows ---
    if (t == 0) {
      while (__hip_atomic_load(&dec_done[s], __ATOMIC_RELAXED,
                               __HIP_MEMORY_SCOPE_AGENT) < CN)
        __builtin_amdgcn_s_sleep(2);
      __builtin_amdgcn_fence(__ATOMIC_ACQUIRE, "agent");
    }
    __syncthreads();
    int c = cnt[s * CA + o];
    for (int base = 0; base < c; base += 4) {
      int nb2 = min(4, c - base);
      if (t < 4) srows[t] = (t < nb2) ? lists[(s * CA + o) * CN + base + t] : -1;
      __syncthreads();
      for (int idx = t; idx < 2048; idx += 512) {
        int row = srows[idx >> 9];
        sxs[idx] = (row >= 0) ? xsbuf[row * 512 + (idx & 511)] : 0.f;
      }
      if (t < nb2) rowsAll[base + t] = srows[t];
      __syncthreads();
      for (int r = 0; r < nb2; ++r) {
        float4 acc; acc.x = acc.y = acc.z = acc.w = 0.f;
        const float* xk = sxs + r * 512 + kq * 32;
        W_EACH(WFM)
        *(float4*)&red[kq * 128 + jl * 4] = acc;
        __syncthreads();
        if (t < 128) {
          float s1 = 0.f;
          #pragma unroll
          for (int q = 0; q < 16; ++q) s1 += red[q * 128 + t];
          sh[t] = fmaxf(s1 + bm1s[t], 0.f);
        }
        __syncthreads();
        if (t < 256) {
          float a2 = 0.f;
          #pragma unroll 16
          for (int jj = 0; jj < 64; ++jj) {
            float2 hv = *(const float2*)&sh[jj * 2];
            float2 wv = *(const float2*)&wm2s[t * 130 + jj * 2];
            a2 = fmaf(hv.x, wv.x, fmaf(hv.y, wv.y, a2));
          }
          int row = srows[r];
          part_db[(((size_t)(s & 1) * CN + row) * 8 + jt) * CE + t] = a2;
        }
        __syncthreads();
      }
    }
    __syncthreads();
    if (t == 0 && c > 0) {
      __builtin_amdgcn_fence(__ATOMIC_RELEASE, "agent");  // flush part writes
      for (int r = 0; r < c; ++r)
        __hip_atomic_fetch_add(&row_done[s * CN + rowsAll[r]], 1,
                               __ATOMIC_RELAXED, __HIP_MEMORY_SCOPE_AGENT);
    }
    // --- fin: epilogue(s) + decision(s+1) ---
    if (bid < CN)
      fin_phase(s + 1, bid, t, P, Wsg, bsg, Wcg, bcg, bm2, part_db, Xout, SLout,
                VALout, PAout, xsbuf, cnt, lists, row_done, dec_done,
                sx, sred, svals, sxtra, sint, logits_s, Xlds);
  }
}

// ---------------------------------------------------------------------------
// embed_loss
// ---------------------------------------------------------------------------
__global__ void el_kernel(const float* __restrict__ emb, const float* __restrict__ Xout,
                          const float* __restrict__ Ws, const float* __restrict__ bsp,
                          float* __restrict__ EL) {
  int tn = blockIdx.x;
  int n = tn & 63;
  int t = threadIdx.x, h = t >> 5, l = t & 31;
  const float* er = emb + (size_t)tn * CE;
  const float* xr = Xout + ((size_t)(n * CHP) + h) * CE;
  float pd = 0.f, px = 0.f, pe = 0.f, ps = 0.f;
  #pragma unroll
  for (int i = 0; i < 8; ++i) {
    int e = l * 8 + i;
    float ev = er[e], xv2 = xr[e];
    pd += ev * xv2; px += xv2 * xv2; pe += ev * ev; ps += fmaxf(ev, 0.f) * Ws[e];
  }
  #pragma unroll
  for (int off = 16; off > 0; off >>= 1) {
    pd += __shfl_down(pd, off, 32);
    px += __shfl_down(px, off, 32);
    pe += __shfl_down(pe, off, 32);
    ps += __shfl_down(ps, off, 32);
  }
  __shared__ float sdot[8], snx[8];
  __shared__ float sne, ssh;
  if (l == 0) {
    sdot[h] = pd;
    snx[h] = sqrtf(px);
    if (h == 0) { sne = sqrtf(pe); ssh = ps + bsp[0]; }
  }
  __syncthreads();
  if (t == 0) {
    const float eps = 1e-8f;
    float y[8];
    float m = -1e30f;
    #pragma unroll
    for (int hh = 0; hh < 8; ++hh) {
      float cs = sdot[hh] / ((sne + eps) * (snx[hh] + eps));
      y[hh] = ssh * cs;
      m = fmaxf(m, y[hh]);
    }
    float sum = 0.f;
    #pragma unroll
    for (int hh = 0; hh < 8; ++hh) sum += expf(y[hh] - m);
    float lse = logf(sum);
    float el = 0.f;
    #pragma unroll
    for (int hh = 0; hh < 8; ++hh) {
      float lp = y[hh] - m - lse;
      el += expf(lp) * lp;
    }
    EL[tn] = el;
  }
}

// ---------------------------------------------------------------------------
extern "C" void kernel_launch(void* const* d_in, const int* in_sizes, int n_in,
                              void* d_out, int out_size, void* d_ws, size_t ws_size,
                              hipStream_t stream) {
  (void)in_sizes; (void)n_in; (void)out_size; (void)ws_size;
  const int*   obs    = (const int*)d_in[0];
  const int*   P      = (const int*)d_in[1];
  const float* embed1 = (const float*)d_in[2];
  const float* Wih    = (const float*)d_in[3];
  // d_in[4] = Whh: provably unused (h0 = 0 and only Hs[0] is consumed)
  const float* bih    = (const float*)d_in[5];
  const float* bhh    = (const float*)d_in[6];
  const float* We2    = (const float*)d_in[7];
  const float* be2    = (const float*)d_in[8];
  const float* Ws     = (const float*)d_in[9];
  const float* bs     = (const float*)d_in[10];
  const float* Wc     = (const float*)d_in[11];
  const float* bc     = (const float*)d_in[12];
  const float* Wm1    = (const float*)d_in[13];
  const float* bm1    = (const float*)d_in[14];
  const float* Wm2    = (const float*)d_in[15];
  const float* bm2    = (const float*)d_in[16];
  const float* eo     = (const float*)d_in[17];
  float* out = (float*)d_out;
  char*  ws  = (char*)d_ws;

  float* emb    = (float*)(ws + B_EMB);
  float* h1     = (float*)(ws + B_H1);
  float* xsp    = (float*)(ws + B_XS);
  float* part_db= (float*)(ws + B_PART);
  int*   cntp   = (int*)(ws + B_CNT);
  int*   decd   = (int*)(ws + B_DEC);
  int*   rowd   = (int*)(ws + B_ROW);
  int*   listp  = (int*)(ws + B_LISTS);
  int*   cnttl  = (int*)(ws + B_CNTTL);
  int*   listtl = (int*)(ws + B_LISTTL);
  float* we2t   = (float*)(ws + B_WE2T);
  float* wm1t   = (float*)(ws + B_WM1T);
  float* xstl   = (float*)(ws + B_XSTL);
  float* hbig   = (float*)(ws + B_HBIG);
  float* parttl = (float*)(ws + B_PARTTL);
  float* wm2t   = (float*)(ws + B_WM2T);
  float* wpm    = (float*)(ws + B_WPM);

  dim3 thr(256);
  init_kernel<<<dim3(514), thr, 0, stream>>>(out, cntp, decd, rowd, cnttl);
  emb_kernel<<<dim3(256), thr, 0, stream>>>(obs, embed1, emb);
  h1_kernel<<<dim3(256), thr, 0, stream>>>(emb, Wih, bih, bhh, h1);
  trans_kernel<<<dim3(16, 4), thr, 0, stream>>>(We2, we2t, CE, CHID);        // We2T
  x0_kernel<<<dim3(4, 64), thr, 0, stream>>>(h1, we2t, be2, out + O_X);
  trans_kernel<<<dim3(128, 16), thr, 0, stream>>>(Wm1, wm1t, CHID, CA * CE); // Wm1T
  wpm_kernel<<<dim3(256, 4), thr, 0, stream>>>(wm1t, eo, wpm);
  trans_kernel<<<dim3(16, 4), thr, 0, stream>>>(Wm2, wm2t, CE, CHID);        // Wm2T
  tllists_kernel<<<dim3(8), thr, 0, stream>>>(P, cnttl, listtl);
  xstl_kernel<<<dim3(4096), thr, 0, stream>>>(emb, xstl);
  // time-loop model (factorized, f32)
  l1_kernel<<<dim3(32, 8, 8), thr, 0, stream>>>(wpm, xstl, bm1, cnttl, listtl, 256, hbig);
  l2big_kernel<<<dim3(8, 64), thr, 0, stream>>>(hbig, wm2t, parttl);
  ml_kernel<<<dim3(2048), thr, 0, stream>>>(parttl, bm2, emb, out + O_ML);
  // planning loop: persistent kernel, producer/consumer flags (no global barrier)
  constexpr size_t PLAN_SMEM = 40336 * sizeof(float);  // 161344 B <= 160 KiB
  plan_kernel<<<dim3(256), dim3(512), PLAN_SMEM, stream>>>(
      wpm, wm2t, bm1, P, Ws, bs, Wc, bc, bm2,
      out + O_X, out + O_SL, out + O_VAL, out + O_PA,
      xsp, cntp, listp, rowd, decd, part_db);
  el_kernel<<<dim3(2048), thr, 0, stream>>>(emb, out + O_X, Ws, bs, out + O_EL);
}

// Round 7
// 882.496 us; speedup vs baseline: 1.0411x; 1.0411x over previous
//
#include <hip/hip_runtime.h>

// ---------------------------------------------------------------------------
// Problem constants
// ---------------------------------------------------------------------------
constexpr int CT = 32;      // T
constexpr int CN = 64;      // N
constexpr int CE = 256;     // E = DOBS*V
constexpr int CHID = 1024;
constexpr int CA = 32;      // num options
constexpr int CS = 32;      // planning steps
constexpr int CHP = 8;      // planning horizon
constexpr int TN = CT * CN; // 2048

// d_out float offsets (return order: search_logits, planned_actions, X, value,
// model_loss, embed_loss)
constexpr size_t O_SL  = 0;        // 32*64*32 = 65536
constexpr size_t O_PA  = 65536;    // 64*8     = 512
constexpr size_t O_X   = 66048;    // 64*8*256 = 131072
constexpr size_t O_VAL = 197120;   // 32*64    = 2048
constexpr size_t O_ML  = 199168;   // 32*64*256= 524288
constexpr size_t O_EL  = 723456;   // 32*64    = 2048

// ws byte offsets (~100 MB total)
constexpr size_t B_EMB    = 0;                           // 2 MB   [2048][256] f32
constexpr size_t B_H1     = 2u * 1024 * 1024;            // 256 KB [64][1024]
constexpr size_t B_XS     = B_H1 + 256 * 1024;           // 128 KB [64][512]
constexpr size_t B_PART   = B_XS + 128 * 1024;           // 1 MB   [2 par][64][8][256]
// control block at 3.5 MB
constexpr size_t B_CNT    = 3584u * 1024;                // 32*32 ints
constexpr size_t B_DEC    = B_CNT + 8 * 1024;            // 32 ints
constexpr size_t B_ROW    = B_DEC + 4 * 1024;            // 32*64 ints
constexpr size_t B_LISTS  = B_ROW + 16 * 1024;           // 32*32*64 ints = 256 KB
constexpr size_t B_CNTTL  = B_LISTS + 272 * 1024;        // 32 ints
constexpr size_t B_LISTTL = B_CNTTL + 4 * 1024;          // 32 KB [32][256]
// 32MB+ multi-phase region: We2T (early) -> Wm1T (mid) -> xstl/hbig/parttl/Wm2T
constexpr size_t B_R32    = 4u * 1024 * 1024;
constexpr size_t B_WE2T   = B_R32;                       // 1 MB  (dead after x0)
constexpr size_t B_WM1T   = B_R32;                       // 32 MB (dead after wpm)
constexpr size_t B_XSTL   = B_R32;                       // 4 MB  [2048][512]
constexpr size_t B_HBIG   = B_R32 + 4u * 1024 * 1024;    // 8 MB  [2048][1024]
constexpr size_t B_PARTTL = B_R32 + 12u * 1024 * 1024;   // 16 MB [2048][8][256]
constexpr size_t B_WM2T   = B_R32 + 28u * 1024 * 1024;   // 1 MB  [1024][256]
constexpr size_t B_WPM    = B_R32 + 32u * 1024 * 1024;   // 64 MB [32][512][1024]

// LDS scalar-state indices for fin blocks
constexpr int SI_FLAG = 0, SI_I = 1, SI_PUSH = 2, SI_IUP = 3;

__device__ __forceinline__ void fma4(float4& a, float s, const float4& w) {
  a.x = fmaf(s, w.x, a.x); a.y = fmaf(s, w.y, a.y);
  a.z = fmaf(s, w.z, a.z); a.w = fmaf(s, w.w, a.w);
}

// ---------------------------------------------------------------------------
// init: zero PA+X span of d_out, per-step counters, flags
// ---------------------------------------------------------------------------
__global__ void init_kernel(float* __restrict__ out, int* __restrict__ cnt,
                            int* __restrict__ dec, int* __restrict__ row,
                            int* __restrict__ cnt_tl) {
  int idx = blockIdx.x * 256 + threadIdx.x;
  if (idx < 131584) out[O_PA + idx] = 0.f;  // PA (512) + X (131072) contiguous
  if (idx < CS * CA) cnt[idx] = 0;
  if (idx < CS) dec[idx] = 0;
  if (idx < CS * CN) row[idx] = 0;
  if (idx < CA) cnt_tl[idx] = 0;
}

// ---------------------------------------------------------------------------
// emb[t][n][e] = embed1[obs[t][n][e>>4]][e&15]
// ---------------------------------------------------------------------------
__global__ void emb_kernel(const int* __restrict__ obs, const float* __restrict__ embed1,
                           float* __restrict__ emb) {
  int idx = blockIdx.x * 256 + threadIdx.x;
  int b = idx >> 5, k8 = idx & 31;
  int e0 = k8 * 8;
  int d = e0 >> 4;
  int o = obs[b * 16 + d];
  const float* src = embed1 + o * 16 + (e0 & 15);
  float4 v0 = *(const float4*)src;
  float4 v1 = *(const float4*)(src + 4);
  float* dst = emb + (size_t)b * CE + e0;
  *(float4*)dst = v0;
  *(float4*)(dst + 4) = v1;
}

// ---------------------------------------------------------------------------
// One GRU step with h0 = 0 (only Hs[0] used downstream; Whh provably unused)
// ---------------------------------------------------------------------------
__global__ void h1_kernel(const float* __restrict__ emb, const float* __restrict__ Wih,
                          const float* __restrict__ bih, const float* __restrict__ bhh,
                          float* __restrict__ h1) {
  int t = threadIdx.x, bid = blockIdx.x;   // 256 blocks of (64n x 4j)
  int n = t & 63, j = bid * 4 + (t >> 6);
  const float* x = emb + (size_t)n * CE;   // emb[0] rows
  const float* wr = Wih + (size_t)j * CE;
  const float* wz = Wih + (size_t)(CHID + j) * CE;
  const float* wn = Wih + (size_t)(2 * CHID + j) * CE;
  float ar = 0.f, az = 0.f, an = 0.f;
  #pragma unroll 4
  for (int e = 0; e < CE; ++e) {
    float xe = x[e];
    ar += xe * wr[e]; az += xe * wz[e]; an += xe * wn[e];
  }
  ar += bih[j] + bhh[j];
  az += bih[CHID + j] + bhh[CHID + j];
  float r = 1.f / (1.f + expf(-ar));
  float z = 1.f / (1.f + expf(-az));
  float nn = tanhf(an + bih[2 * CHID + j] + r * bhh[2 * CHID + j]);
  h1[(size_t)n * CHID + j] = (1.f - z) * nn;
}

// ---------------------------------------------------------------------------
// Generic 64x64 tiled transpose: in[R][C] -> out[C][R]
// ---------------------------------------------------------------------------
__global__ void trans_kernel(const float* __restrict__ in, float* __restrict__ out,
                             int R, int C) {
  __shared__ float tile[64][65];
  int tj = threadIdx.x & 63, tg = threadIdx.x >> 6;
  int cb = blockIdx.x * 64, rb = blockIdx.y * 64;
  #pragma unroll
  for (int i = 0; i < 16; ++i) {
    int r = tg * 16 + i;
    tile[r][tj] = in[(size_t)(rb + r) * C + cb + tj];
  }
  __syncthreads();
  #pragma unroll
  for (int i = 0; i < 16; ++i) {
    int c2 = tg * 16 + i;
    out[(size_t)(cb + c2) * R + rb + tj] = tile[tj][c2];
  }
}

// ---------------------------------------------------------------------------
// X[:,0] = h1 @ We2^T + be2   (We2T layout [k][e])
// ---------------------------------------------------------------------------
__global__ void x0_kernel(const float* __restrict__ h1, const float* __restrict__ We2T,
                          const float* __restrict__ be2, float* __restrict__ Xout) {
  int et = blockIdx.x, n = blockIdx.y, t = threadIdx.x;
  int el = t & 63, kq = t >> 6;
  __shared__ float hr[1024];
  __shared__ float sred2[4][64];
  for (int idx = t; idx < 1024; idx += 256) hr[idx] = h1[(size_t)n * CHID + idx];
  __syncthreads();
  int e = et * 64 + el;
  float acc = 0.f;
  for (int k = kq * 256; k < kq * 256 + 256; ++k) acc += hr[k] * We2T[(size_t)k * CE + e];
  sred2[kq][el] = acc;
  __syncthreads();
  if (t < 64) {
    float s2 = sred2[0][t] + sred2[1][t] + sred2[2][t] + sred2[3][t] + be2[et * 64 + t];
    Xout[(size_t)(n * CHP) * CE + et * 64 + t] = s2;
  }
}

// ---------------------------------------------------------------------------
// Factorized model weights:
// Wpm[o][e][j]     = sum_a relu( embed_opt[o][a]) * Wm1[j][a*256+e]
// Wpm[o][256+e][j] = sum_a relu(-embed_opt[o][a]) * Wm1[j][a*256+e]
// ---------------------------------------------------------------------------
__global__ void wpm_kernel(const float* __restrict__ Wm1T, const float* __restrict__ eo,
                           float* __restrict__ Wpm) {
  int e = blockIdx.x, jt = blockIdx.y, t = threadIdx.x;
  int j = jt * 256 + t;
  __shared__ float rp[CA * CA], rm[CA * CA];
  for (int idx = t; idx < CA * CA; idx += 256) {
    float v = eo[idx];
    rp[idx] = fmaxf(v, 0.f);
    rm[idx] = fmaxf(-v, 0.f);
  }
  __syncthreads();
  float w[32];
  #pragma unroll
  for (int a = 0; a < 32; ++a) w[a] = Wm1T[(size_t)(a * 256 + e) * CHID + j];
  for (int o = 0; o < 32; ++o) {
    float sp = 0.f, sm = 0.f;
    #pragma unroll
    for (int a = 0; a < 32; ++a) {
      float wa = w[a];
      sp += rp[o * 32 + a] * wa;
      sm += rm[o * 32 + a] * wa;
    }
    Wpm[((size_t)o * 512 + e) * CHID + j] = sp;
    Wpm[((size_t)o * 512 + 256 + e) * CHID + j] = sm;
  }
}

// ---------------------------------------------------------------------------
// Group time-loop rows by option (list order nondeterministic; results aren't)
// ---------------------------------------------------------------------------
__global__ void tllists_kernel(const int* __restrict__ P, int* __restrict__ cnt_tl,
                               int* __restrict__ list_tl) {
  int b = blockIdx.x * 256 + threadIdx.x;
  if (b >= TN) return;
  int a = P[b];
  int slot = atomicAdd(&cnt_tl[a], 1);
  list_tl[a * 256 + slot] = b;
}

// xs_tl[b][k] = relu(+/- prev[b][k&255]),  prev = emb shifted by one t (wrap)
__global__ void xstl_kernel(const float* __restrict__ emb, float* __restrict__ xs) {
  int idx = blockIdx.x * 256 + threadIdx.x;   // < 2048*512
  int b = idx >> 9, k = idx & 511;
  int e = k & 255;
  int bp = (b < CN) ? (b + (CT - 1) * CN) : (b - CN);
  float v = emb[(size_t)bp * CE + e];
  xs[idx] = (k < 256) ? fmaxf(v, 0.f) : fmaxf(-v, 0.f);
}

// ---------------------------------------------------------------------------
// Time-loop factorized model layer 1:
// h[row][j] = relu( sum_{k<512} xs[row][k] * Wpm[o][k][j] + bm1[j] )
// grid (32 o, 8 j-tiles of 128, z row-group start)
// ---------------------------------------------------------------------------
__global__ __launch_bounds__(256) void l1_kernel(
    const float* __restrict__ Wpm, const float* __restrict__ xs,
    const float* __restrict__ bm1, const int* __restrict__ cnt,
    const int* __restrict__ list, int listStride, float* __restrict__ hout) {
  int o = blockIdx.x, jt = blockIdx.y;
  int c = cnt[o];
  if (c <= 0) return;
  __shared__ __align__(16) float sbuf[8192];
  __shared__ int srows[8];
  int t = threadIdx.x;
  int jl = t & 31, kq = t >> 5;
  int jb = jt * 128;
  const float* wb = Wpm + (size_t)o * (512 * CHID) + jb + jl * 4;
  for (int g = blockIdx.z; g * 8 < c; g += gridDim.z) {
    int base = g * 8;
    int nr = min(8, c - base);
    if (t < 8) srows[t] = (t < nr) ? list[o * listStride + base + t] : -1;
    __syncthreads();
    for (int idx = t; idx < 4096; idx += 256) {
      int row = srows[idx >> 9];
      sbuf[idx] = (row >= 0) ? xs[(size_t)row * 512 + (idx & 511)] : 0.f;
    }
    __syncthreads();
    float4 acc[8];
    #pragma unroll
    for (int r = 0; r < 8; ++r) acc[r] = make_float4(0.f, 0.f, 0.f, 0.f);
    int kbase = kq * 64;
    for (int k4 = 0; k4 < 64; k4 += 4) {
      int k = kbase + k4;
      float4 w0 = *(const float4*)(wb + (size_t)(k + 0) * CHID);
      float4 w1 = *(const float4*)(wb + (size_t)(k + 1) * CHID);
      float4 w2 = *(const float4*)(wb + (size_t)(k + 2) * CHID);
      float4 w3 = *(const float4*)(wb + (size_t)(k + 3) * CHID);
      #pragma unroll
      for (int r = 0; r < 8; ++r) {
        float4 xv = *(const float4*)&sbuf[r * 512 + k];
        fma4(acc[r], xv.x, w0); fma4(acc[r], xv.y, w1);
        fma4(acc[r], xv.z, w2); fma4(acc[r], xv.w, w3);
      }
    }
    __syncthreads();
    #pragma unroll
    for (int r = 0; r < 8; ++r)
      *(float4*)&sbuf[(kq * 8 + r) * 128 + jl * 4] = acc[r];
    __syncthreads();
    for (int idx = t; idx < 1024; idx += 256) {
      int r = idx >> 7, jc = idx & 127;
      float s = 0.f;
      #pragma unroll
      for (int q = 0; q < 8; ++q) s += sbuf[(q * 8 + r) * 128 + jc];
      int row = srows[r];
      if (row >= 0)
        hout[(size_t)row * CHID + jb + jc] = fmaxf(s + bm1[jb + jc], 0.f);
    }
    __syncthreads();
  }
}

// ---------------------------------------------------------------------------
// Time-loop layer 2 partials: part[b][kq][e], 8 k-slices of 128
// grid (8 kq, 64 row-groups of 32), 256 thr (= e)
// ---------------------------------------------------------------------------
__global__ __launch_bounds__(256) void l2big_kernel(const float* __restrict__ h,
    const float* __restrict__ Wm2T, float* __restrict__ part) {
  int kq = blockIdx.x, rg = blockIdx.y, t = threadIdx.x;
  int rb = rg * 32, kb = kq * 128;
  __shared__ __align__(16) float hl[4096];
  for (int idx = t; idx < 4096; idx += 256)
    hl[idx] = h[(size_t)(rb + (idx >> 7)) * CHID + kb + (idx & 127)];
  __syncthreads();
  float acc[32];
  #pragma unroll
  for (int r = 0; r < 32; ++r) acc[r] = 0.f;
  for (int kk = 0; kk < 128; kk += 4) {
    float w0 = Wm2T[(size_t)(kb + kk + 0) * CE + t];
    float w1 = Wm2T[(size_t)(kb + kk + 1) * CE + t];
    float w2 = Wm2T[(size_t)(kb + kk + 2) * CE + t];
    float w3 = Wm2T[(size_t)(kb + kk + 3) * CE + t];
    #pragma unroll
    for (int r = 0; r < 32; ++r) {
      float4 hv = *(const float4*)&hl[r * 128 + kk];
      acc[r] += hv.x * w0 + hv.y * w1 + hv.z * w2 + hv.w * w3;
    }
  }
  #pragma unroll
  for (int r = 0; r < 32; ++r)
    part[((size_t)(rb + r) * 8 + kq) * CE + t] = acc[r];
}

// model_loss = (sum(partials)+bm2 - emb)^2
__global__ void ml_kernel(const float* __restrict__ part, const float* __restrict__ bm2,
                          const float* __restrict__ emb, float* __restrict__ ML) {
  int idx = blockIdx.x * 256 + threadIdx.x;   // < 2048*256
  int b = idx >> 8, e = idx & 255;
  float outv = bm2[e];
  #pragma unroll
  for (int q = 0; q < 8; ++q) outv += part[((size_t)b * 8 + q) * CE + e];
  float d = outv - emb[idx];
  ML[idx] = d * d;
}

// ---------------------------------------------------------------------------
// fin phase (blocks 0..63, n = bid): epilogue of step s-1 + decision of step s.
// Per-n state (I, push, Iup, logits, X copy) lives in block LDS. Cross-block:
// spin row_done[s-1][n]==8 (only if pushed), part_db reads, xs/cnt/lists
// writes, release-fence + dec_done[s] arrive. s==CS: epilogue only.
// ---------------------------------------------------------------------------
__device__ __forceinline__ void fin_phase(
    int s, int n, int t,
    const int* __restrict__ P, const float* __restrict__ Wsg,
    const float* __restrict__ bsg, const float* __restrict__ Wcg,
    const float* __restrict__ bcg, const float* __restrict__ bm2,
    const float* __restrict__ part_db, float* __restrict__ Xout,
    float* __restrict__ SLout, float* __restrict__ VALout,
    float* __restrict__ PAout, float* __restrict__ xsbuf,
    int* __restrict__ cnt, int* __restrict__ lists,
    int* __restrict__ row_done, int* __restrict__ dec_done,
    float* sx, float* sred, float* svals, float* sxtra, int* sint,
    float* logits_s, float* Xlds) {
  // Read-only prefetch, issued BEFORE the spin (inputs never written -> no
  // staleness); latency hides under the dependency wait.
  float wsv = 0.f, bm2v = 0.f, bcv = 0.f, bsv = bsg[0];
  float wcv[32];
  int c2 = t >> 3, g = t & 7;
  if (t < 256) {
    wsv = Wsg[t]; bm2v = bm2[t];
    #pragma unroll
    for (int i = 0; i < 32; ++i) wcv[i] = Wcg[c2 * CE + g * 32 + i];
  }
  if (t < CA) bcv = bcg[t];

  if (s > 0) {
    int push = sint[SI_PUSH];
    if (push) {
      if (t == 0) {
        int* rd = &row_done[(s - 1) * CN + n];
        while (__hip_atomic_load(rd, __ATOMIC_RELAXED, __HIP_MEMORY_SCOPE_AGENT) < 8)
          __builtin_amdgcn_s_sleep(1);
        __builtin_amdgcn_fence(__ATOMIC_ACQUIRE, "agent");
      }
      __syncthreads();
      int Iup = sint[SI_IUP];
      if (t < 256) {
        const float* pb = part_db + (((size_t)((s - 1) & 1) * CN + n) * 8) * CE + t;
        float outv = bm2v;
        #pragma unroll
        for (int q = 0; q < 8; ++q) outv += pb[(size_t)q * CE];
        Xlds[Iup * CE + t] = outv;
        Xout[((size_t)(n * CHP) + Iup) * CE + t] = outv;
        sx[t] = outv;
      }
      if (t == 0) sint[SI_I] = Iup;
    } else {
      int I = sint[SI_I];
      int Inew = (I - 1 > 0) ? I - 1 : 0;
      if (t < 256) sx[t] = Xlds[Inew * CE + t];
      if (t == 0) sint[SI_I] = Inew;
    }
    if (s == CS) return;  // final epilogue only (uniform)
  } else {
    if (t < 256) sx[t] = Xlds[t];
    if (t == 0) sint[SI_I] = 0;
  }
  __syncthreads();
  int I = sint[SI_I];
  if (t < 256) {
    float xv = sx[t];
    float xa = fmaxf(xv, 0.f);
    xsbuf[n * 512 + t] = xa;
    xsbuf[n * 512 + 256 + t] = fmaxf(-xv, 0.f);
    sred[t] = xa * wsv;
  }
  __syncthreads();
  #pragma unroll
  for (int off = 128; off > 0; off >>= 1) {
    if (t < off) sred[t] += sred[t + off];
    __syncthreads();
  }
  if (t == 0) { sxtra[0] = sred[0] + bsv; sint[SI_FLAG] = 1; }
  if (t < 256) {
    float pv = 0.f;
    #pragma unroll 4
    for (int i = 0; i < 32; ++i)
      pv += fmaxf(sx[g * 32 + i], 0.f) * wcv[i];
    pv += __shfl_down(pv, 4, 8);
    pv += __shfl_down(pv, 2, 8);
    pv += __shfl_down(pv, 1, 8);
    if (g == 0) svals[c2] = pv + bcv;
  }
  __syncthreads();
  if (t < CA && logits_s[t] != 0.f) sint[SI_FLAG] = 0;
  __syncthreads();
  int a = P[s * CN + n];
  if (t < CA) {
    float v = svals[t];
    float slv = sint[SI_FLAG] ? sxtra[0] * v : logits_s[t];
    SLout[(size_t)(s * CN + n) * CA + t] = slv;
    logits_s[t] = slv - (t == a ? 1e8f : 0.f);
    if (t == a) {
      VALout[s * CN + n] = slv;
      int pn = (v > 0.f) ? 1 : 0;
      sint[SI_PUSH] = pn;
      PAout[n * CHP + I] = (float)a;
      sint[SI_IUP] = (I + 1 < CHP - 1) ? I + 1 : CHP - 1;
      if (pn) {
        int slot = atomicAdd(&cnt[s * CA + a], 1);
        lists[(s * CA + a) * CN + slot] = n;
      }
    }
  }
  __syncthreads();
  if (t == 0) {
    __builtin_amdgcn_fence(__ATOMIC_RELEASE, "agent");   // flush xs/lists/outputs
    __hip_atomic_fetch_add(&dec_done[s], 1, __ATOMIC_RELAXED, __HIP_MEMORY_SCOPE_AGENT);
  }
  __syncthreads();
}

// ---------------------------------------------------------------------------
// Persistent planning kernel: 256 blocks x 512 threads (1 block/CU, LDS-forced).
// Block (o,jt): Wpm[o][:, jb..jb+128) in 32 NAMED float4 registers per thread.
// Round-5/6 post-mortem: the allocator targets default occupancy (128-VGPR
// budget; dynamic LDS hides the 1-block/CU limit) and REMATERIALIZES the
// read-only W loads into the loop as global re-reads (VGPR_Count stuck at
// 124). Fix:
//   (1) amdgpu_waves_per_eu(2,2): pin occupancy target to 2 waves/EU -> 256
//       VGPR budget (matches true LDS-forced residency: 8 waves/CU).
//   (2) per-COMPONENT asm "+v" pin after the loads (float4 operands are
//       indirect and unsupported -> round-6 compile fail; scalars are direct):
//       values become asm-defined, compiler cannot remat them from memory.
// No global barrier: dec_done / row_done producer-consumer counters.
// ---------------------------------------------------------------------------
#define W_EACH(M) M(0) M(1) M(2) M(3) M(4) M(5) M(6) M(7) M(8) M(9) M(10) \
  M(11) M(12) M(13) M(14) M(15) M(16) M(17) M(18) M(19) M(20) M(21) M(22) \
  M(23) M(24) M(25) M(26) M(27) M(28) M(29) M(30) M(31)
#define WLD(i) float4 W##i = *(const float4*)(wsrc + (size_t)(i) * CHID);
#define WPIN(i) asm volatile("" : "+v"(W##i.x), "+v"(W##i.y), \
                                   "+v"(W##i.z), "+v"(W##i.w));
#define WFM(i) { float xv_ = xk[i]; \
  acc.x = fmaf(xv_, W##i.x, acc.x); acc.y = fmaf(xv_, W##i.y, acc.y); \
  acc.z = fmaf(xv_, W##i.z, acc.z); acc.w = fmaf(xv_, W##i.w, acc.w); }

__global__ void
__attribute__((amdgpu_flat_work_group_size(512, 512), amdgpu_waves_per_eu(2, 2)))
plan_kernel(
    const float* __restrict__ Wpm, const float* __restrict__ Wm2T,
    const float* __restrict__ bm1g, const int* __restrict__ P,
    const float* Wsg, const float* bsg, const float* Wcg, const float* bcg,
    const float* bm2, float* Xout, float* SLout, float* VALout, float* PAout,
    float* xsbuf, int* cnt, int* lists, int* row_done, int* dec_done,
    float* part_db) {
  extern __shared__ float smem[];
  float* wm2s    = smem;                  // [256 e][130 pad] = 33280
  float* bm1s    = wm2s + 33280;          // 128
  float* red     = bm1s + 128;            // 16*128 = 2048
  float* sh      = red + 2048;            // 128
  float* sxs     = sh + 128;              // 4*512 = 2048
  float* sx      = sxs + 2048;            // 256
  float* sred    = sx + 256;              // 256
  float* svals   = sred + 256;            // 32
  float* sxtra   = svals + 32;            // 4
  int*   sint    = (int*)(sxtra + 4);     // 8
  int*   srows   = sint + 8;              // 4
  int*   rowsAll = srows + 4;             // 64
  float* logits_s= (float*)(rowsAll + 64);// 32
  float* Xlds    = logits_s + 32;         // 2048
  // total 40336 floats = 161344 B <= 160 KiB

  int bid = blockIdx.x, t = threadIdx.x;
  int o = bid >> 3, jt = bid & 7;
  int jl = t & 31, kq = t >> 5;           // kq in [0,16): 32 k each
  int jb = jt * 128;

  // --- prologue: weights resident in NAMED registers + LDS ---
  const float* wsrc = Wpm + ((size_t)o * 512 + (size_t)kq * 32) * CHID + jb + jl * 4;
  W_EACH(WLD)
  W_EACH(WPIN)
  for (int idx = t; idx < 128 * 256; idx += 512) {
    int e = idx & 255, j = idx >> 8;
    wm2s[e * 130 + j] = Wm2T[(size_t)(jb + j) * CE + e];
  }
  if (t < 128) bm1s[t] = bm1g[jb + t];
  if (bid < CN) {
    for (int idx = t; idx < CHP * CE; idx += 512)
      Xlds[idx] = Xout[(size_t)bid * (CHP * CE) + idx];
    if (t < 32) logits_s[t] = 0.f;
    if (t < 8) sint[t] = 0;
  }
  __syncthreads();

  if (bid < CN)
    fin_phase(0, bid, t, P, Wsg, bsg, Wcg, bcg, bm2, part_db, Xout, SLout,
              VALout, PAout, xsbuf, cnt, lists, row_done, dec_done,
              sx, sred, svals, sxtra, sint, logits_s, Xlds);

  for (int s = 0; s < CS; ++s) {
    // --- phase A: wait decisions, run l1+l2 for this option's pushed rows ---
    if (t == 0) {
      while (__hip_atomic_load(&dec_done[s], __ATOMIC_RELAXED,
                               __HIP_MEMORY_SCOPE_AGENT) < CN)
        __builtin_amdgcn_s_sleep(2);
      __builtin_amdgcn_fence(__ATOMIC_ACQUIRE, "agent");
    }
    __syncthreads();
    int c = cnt[s * CA + o];
    for (int base = 0; base < c; base += 4) {
      int nb2 = min(4, c - base);
      if (t < 4) srows[t] = (t < nb2) ? lists[(s * CA + o) * CN + base + t] : -1;
      __syncthreads();
      for (int idx = t; idx < 2048; idx += 512) {
        int row = srows[idx >> 9];
        sxs[idx] = (row >= 0) ? xsbuf[row * 512 + (idx & 511)] : 0.f;
      }
      if (t < nb2) rowsAll[base + t] = srows[t];
      __syncthreads();
      for (int r = 0; r < nb2; ++r) {
        float4 acc; acc.x = acc.y = acc.z = acc.w = 0.f;
        const float* xk = sxs + r * 512 + kq * 32;
        W_EACH(WFM)
        *(float4*)&red[kq * 128 + jl * 4] = acc;
        __syncthreads();
        if (t < 128) {
          float s1 = 0.f;
          #pragma unroll
          for (int q = 0; q < 16; ++q) s1 += red[q * 128 + t];
          sh[t] = fmaxf(s1 + bm1s[t], 0.f);
        }
        __syncthreads();
        if (t < 256) {
          float a2 = 0.f;
          #pragma unroll 16
          for (int jj = 0; jj < 64; ++jj) {
            float2 hv = *(const float2*)&sh[jj * 2];
            float2 wv = *(const float2*)&wm2s[t * 130 + jj * 2];
            a2 = fmaf(hv.x, wv.x, fmaf(hv.y, wv.y, a2));
          }
          int row = srows[r];
          part_db[(((size_t)(s & 1) * CN + row) * 8 + jt) * CE + t] = a2;
        }
        __syncthreads();
      }
    }
    __syncthreads();
    if (t == 0 && c > 0) {
      __builtin_amdgcn_fence(__ATOMIC_RELEASE, "agent");  // flush part writes
      for (int r = 0; r < c; ++r)
        __hip_atomic_fetch_add(&row_done[s * CN + rowsAll[r]], 1,
                               __ATOMIC_RELAXED, __HIP_MEMORY_SCOPE_AGENT);
    }
    // --- fin: epilogue(s) + decision(s+1) ---
    if (bid < CN)
      fin_phase(s + 1, bid, t, P, Wsg, bsg, Wcg, bcg, bm2, part_db, Xout, SLout,
                VALout, PAout, xsbuf, cnt, lists, row_done, dec_done,
                sx, sred, svals, sxtra, sint, logits_s, Xlds);
  }
}

// ---------------------------------------------------------------------------
// embed_loss
// ---------------------------------------------------------------------------
__global__ void el_kernel(const float* __restrict__ emb, const float* __restrict__ Xout,
                          const float* __restrict__ Ws, const float* __restrict__ bsp,
                          float* __restrict__ EL) {
  int tn = blockIdx.x;
  int n = tn & 63;
  int t = threadIdx.x, h = t >> 5, l = t & 31;
  const float* er = emb + (size_t)tn * CE;
  const float* xr = Xout + ((size_t)(n * CHP) + h) * CE;
  float pd = 0.f, px = 0.f, pe = 0.f, ps = 0.f;
  #pragma unroll
  for (int i = 0; i < 8; ++i) {
    int e = l * 8 + i;
    float ev = er[e], xv2 = xr[e];
    pd += ev * xv2; px += xv2 * xv2; pe += ev * ev; ps += fmaxf(ev, 0.f) * Ws[e];
  }
  #pragma unroll
  for (int off = 16; off > 0; off >>= 1) {
    pd += __shfl_down(pd, off, 32);
    px += __shfl_down(px, off, 32);
    pe += __shfl_down(pe, off, 32);
    ps += __shfl_down(ps, off, 32);
  }
  __shared__ float sdot[8], snx[8];
  __shared__ float sne, ssh;
  if (l == 0) {
    sdot[h] = pd;
    snx[h] = sqrtf(px);
    if (h == 0) { sne = sqrtf(pe); ssh = ps + bsp[0]; }
  }
  __syncthreads();
  if (t == 0) {
    const float eps = 1e-8f;
    float y[8];
    float m = -1e30f;
    #pragma unroll
    for (int hh = 0; hh < 8; ++hh) {
      float cs = sdot[hh] / ((sne + eps) * (snx[hh] + eps));
      y[hh] = ssh * cs;
      m = fmaxf(m, y[hh]);
    }
    float sum = 0.f;
    #pragma unroll
    for (int hh = 0; hh < 8; ++hh) sum += expf(y[hh] - m);
    float lse = logf(sum);
    float el = 0.f;
    #pragma unroll
    for (int hh = 0; hh < 8; ++hh) {
      float lp = y[hh] - m - lse;
      el += expf(lp) * lp;
    }
    EL[tn] = el;
  }
}

// ---------------------------------------------------------------------------
extern "C" void kernel_launch(void* const* d_in, const int* in_sizes, int n_in,
                              void* d_out, int out_size, void* d_ws, size_t ws_size,
                              hipStream_t stream) {
  (void)in_sizes; (void)n_in; (void)out_size; (void)ws_size;
  const int*   obs    = (const int*)d_in[0];
  const int*   P      = (const int*)d_in[1];
  const float* embed1 = (const float*)d_in[2];
  const float* Wih    = (const float*)d_in[3];
  // d_in[4] = Whh: provably unused (h0 = 0 and only Hs[0] is consumed)
  const float* bih    = (const float*)d_in[5];
  const float* bhh    = (const float*)d_in[6];
  const float* We2    = (const float*)d_in[7];
  const float* be2    = (const float*)d_in[8];
  const float* Ws     = (const float*)d_in[9];
  const float* bs     = (const float*)d_in[10];
  const float* Wc     = (const float*)d_in[11];
  const float* bc     = (const float*)d_in[12];
  const float* Wm1    = (const float*)d_in[13];
  const float* bm1    = (const float*)d_in[14];
  const float* Wm2    = (const float*)d_in[15];
  const float* bm2    = (const float*)d_in[16];
  const float* eo     = (const float*)d_in[17];
  float* out = (float*)d_out;
  char*  ws  = (char*)d_ws;

  float* emb    = (float*)(ws + B_EMB);
  float* h1     = (float*)(ws + B_H1);
  float* xsp    = (float*)(ws + B_XS);
  float* part_db= (float*)(ws + B_PART);
  int*   cntp   = (int*)(ws + B_CNT);
  int*   decd   = (int*)(ws + B_DEC);
  int*   rowd   = (int*)(ws + B_ROW);
  int*   listp  = (int*)(ws + B_LISTS);
  int*   cnttl  = (int*)(ws + B_CNTTL);
  int*   listtl = (int*)(ws + B_LISTTL);
  float* we2t   = (float*)(ws + B_WE2T);
  float* wm1t   = (float*)(ws + B_WM1T);
  float* xstl   = (float*)(ws + B_XSTL);
  float* hbig   = (float*)(ws + B_HBIG);
  float* parttl = (float*)(ws + B_PARTTL);
  float* wm2t   = (float*)(ws + B_WM2T);
  float* wpm    = (float*)(ws + B_WPM);

  dim3 thr(256);
  init_kernel<<<dim3(514), thr, 0, stream>>>(out, cntp, decd, rowd, cnttl);
  emb_kernel<<<dim3(256), thr, 0, stream>>>(obs, embed1, emb);
  h1_kernel<<<dim3(256), thr, 0, stream>>>(emb, Wih, bih, bhh, h1);
  trans_kernel<<<dim3(16, 4), thr, 0, stream>>>(We2, we2t, CE, CHID);        // We2T
  x0_kernel<<<dim3(4, 64), thr, 0, stream>>>(h1, we2t, be2, out + O_X);
  trans_kernel<<<dim3(128, 16), thr, 0, stream>>>(Wm1, wm1t, CHID, CA * CE); // Wm1T
  wpm_kernel<<<dim3(256, 4), thr, 0, stream>>>(wm1t, eo, wpm);
  trans_kernel<<<dim3(16, 4), thr, 0, stream>>>(Wm2, wm2t, CE, CHID);        // Wm2T
  tllists_kernel<<<dim3(8), thr, 0, stream>>>(P, cnttl, listtl);
  xstl_kernel<<<dim3(4096), thr, 0, stream>>>(emb, xstl);
  // time-loop model (factorized, f32)
  l1_kernel<<<dim3(32, 8, 8), thr, 0, stream>>>(wpm, xstl, bm1, cnttl, listtl, 256, hbig);
  l2big_kernel<<<dim3(8, 64), thr, 0, stream>>>(hbig, wm2t, parttl);
  ml_kernel<<<dim3(2048), thr, 0, stream>>>(parttl, bm2, emb, out + O_ML);
  // planning loop: persistent kernel, producer/consumer flags (no global barrier)
  constexpr size_t PLAN_SMEM = 40336 * sizeof(float);  // 161344 B <= 160 KiB
  plan_kernel<<<dim3(256), dim3(512), PLAN_SMEM, stream>>>(
      wpm, wm2t, bm1, P, Ws, bs, Wc, bc, bm2,
      out + O_X, out + O_SL, out + O_VAL, out + O_PA,
      xsp, cntp, listp, rowd, decd, part_db);
  el_kernel<<<dim3(2048), thr, 0, stream>>>(emb, out + O_X, Ws, bs, out + O_EL);
}

// Round 8
// 879.977 us; speedup vs baseline: 1.0441x; 1.0029x over previous
//
#include <hip/hip_runtime.h>

// ---------------------------------------------------------------------------
// Problem constants
// ---------------------------------------------------------------------------
constexpr int CT = 32;      // T
constexpr int CN = 64;      // N
constexpr int CE = 256;     // E = DOBS*V
constexpr int CHID = 1024;
constexpr int CA = 32;      // num options
constexpr int CS = 32;      // planning steps
constexpr int CHP = 8;      // planning horizon
constexpr int TN = CT * CN; // 2048

// d_out float offsets (return order: search_logits, planned_actions, X, value,
// model_loss, embed_loss)
constexpr size_t O_SL  = 0;        // 32*64*32 = 65536
constexpr size_t O_PA  = 65536;    // 64*8     = 512
constexpr size_t O_X   = 66048;    // 64*8*256 = 131072
constexpr size_t O_VAL = 197120;   // 32*64    = 2048
constexpr size_t O_ML  = 199168;   // 32*64*256= 524288
constexpr size_t O_EL  = 723456;   // 32*64    = 2048

// ws byte offsets (~100 MB total)
constexpr size_t B_EMB    = 0;                           // 2 MB   [2048][256] f32
constexpr size_t B_H1     = 2u * 1024 * 1024;            // 256 KB [64][1024]
constexpr size_t B_XS     = B_H1 + 256 * 1024;           // 128 KB [64][512]
constexpr size_t B_PART   = B_XS + 128 * 1024;           // 1 MB   [2 par][64][8][256]
// control block at 3.5 MB
constexpr size_t B_CNT    = 3584u * 1024;                // 32*32 ints
constexpr size_t B_DEC    = B_CNT + 8 * 1024;            // 32 ints
constexpr size_t B_ROW    = B_DEC + 4 * 1024;            // 32*64 ints
constexpr size_t B_LISTS  = B_ROW + 16 * 1024;           // 32*32*64 ints = 256 KB
constexpr size_t B_CNTTL  = B_LISTS + 272 * 1024;        // 32 ints
constexpr size_t B_LISTTL = B_CNTTL + 4 * 1024;          // 32 KB [32][256]
// 32MB+ multi-phase region: We2T (early) -> Wm1T (mid) -> xstl/hbig/parttl/Wm2T
constexpr size_t B_R32    = 4u * 1024 * 1024;
constexpr size_t B_WE2T   = B_R32;                       // 1 MB  (dead after x0)
constexpr size_t B_WM1T   = B_R32;                       // 32 MB (dead after wpm)
constexpr size_t B_XSTL   = B_R32;                       // 4 MB  [2048][512]
constexpr size_t B_HBIG   = B_R32 + 4u * 1024 * 1024;    // 8 MB  [2048][1024]
constexpr size_t B_PARTTL = B_R32 + 12u * 1024 * 1024;   // 16 MB [2048][8][256]
constexpr size_t B_WM2T   = B_R32 + 28u * 1024 * 1024;   // 1 MB  [1024][256]
constexpr size_t B_WPM    = B_R32 + 32u * 1024 * 1024;   // 64 MB [32][512][1024]

// LDS scalar-state indices for fin blocks
constexpr int SI_FLAG = 0, SI_I = 1, SI_PUSH = 2, SI_IUP = 3;

__device__ __forceinline__ void fma4(float4& a, float s, const float4& w) {
  a.x = fmaf(s, w.x, a.x); a.y = fmaf(s, w.y, a.y);
  a.z = fmaf(s, w.z, a.z); a.w = fmaf(s, w.w, a.w);
}

// ---------------------------------------------------------------------------
// LLC-coherent (L2-bypassing) accessors for cross-block data. Relaxed agent-
// scope atomics operate at the coherence point (LLC) -> no fences needed, and
// the per-XCD L2s are never invalidated (read-only weights stay warm).
// Producer ordering: __syncthreads drains vmcnt before s_barrier (per-thread
// store completion), so a post-barrier flag add orders after all data stores.
// ---------------------------------------------------------------------------
__device__ __forceinline__ float gld(const float* p) {
  return __hip_atomic_load(p, __ATOMIC_RELAXED, __HIP_MEMORY_SCOPE_AGENT);
}
__device__ __forceinline__ void gst(float* p, float v) {
  __hip_atomic_store(p, v, __ATOMIC_RELAXED, __HIP_MEMORY_SCOPE_AGENT);
}
__device__ __forceinline__ int gldi(const int* p) {
  return __hip_atomic_load(p, __ATOMIC_RELAXED, __HIP_MEMORY_SCOPE_AGENT);
}
__device__ __forceinline__ void gsti(int* p, int v) {
  __hip_atomic_store(p, v, __ATOMIC_RELAXED, __HIP_MEMORY_SCOPE_AGENT);
}
__device__ __forceinline__ void waitst() {
  asm volatile("s_waitcnt vmcnt(0)" ::: "memory");
}

// ---------------------------------------------------------------------------
// init: zero PA+X span of d_out, per-step counters, flags
// ---------------------------------------------------------------------------
__global__ void init_kernel(float* __restrict__ out, int* __restrict__ cnt,
                            int* __restrict__ dec, int* __restrict__ row,
                            int* __restrict__ cnt_tl) {
  int idx = blockIdx.x * 256 + threadIdx.x;
  if (idx < 131584) out[O_PA + idx] = 0.f;  // PA (512) + X (131072) contiguous
  if (idx < CS * CA) cnt[idx] = 0;
  if (idx < CS) dec[idx] = 0;
  if (idx < CS * CN) row[idx] = 0;
  if (idx < CA) cnt_tl[idx] = 0;
}

// ---------------------------------------------------------------------------
// emb[t][n][e] = embed1[obs[t][n][e>>4]][e&15]
// ---------------------------------------------------------------------------
__global__ void emb_kernel(const int* __restrict__ obs, const float* __restrict__ embed1,
                           float* __restrict__ emb) {
  int idx = blockIdx.x * 256 + threadIdx.x;
  int b = idx >> 5, k8 = idx & 31;
  int e0 = k8 * 8;
  int d = e0 >> 4;
  int o = obs[b * 16 + d];
  const float* src = embed1 + o * 16 + (e0 & 15);
  float4 v0 = *(const float4*)src;
  float4 v1 = *(const float4*)(src + 4);
  float* dst = emb + (size_t)b * CE + e0;
  *(float4*)dst = v0;
  *(float4*)(dst + 4) = v1;
}

// ---------------------------------------------------------------------------
// One GRU step with h0 = 0 (only Hs[0] used downstream; Whh provably unused)
// ---------------------------------------------------------------------------
__global__ void h1_kernel(const float* __restrict__ emb, const float* __restrict__ Wih,
                          const float* __restrict__ bih, const float* __restrict__ bhh,
                          float* __restrict__ h1) {
  int t = threadIdx.x, bid = blockIdx.x;   // 256 blocks of (64n x 4j)
  int n = t & 63, j = bid * 4 + (t >> 6);
  const float* x = emb + (size_t)n * CE;   // emb[0] rows
  const float* wr = Wih + (size_t)j * CE;
  const float* wz = Wih + (size_t)(CHID + j) * CE;
  const float* wn = Wih + (size_t)(2 * CHID + j) * CE;
  float ar = 0.f, az = 0.f, an = 0.f;
  #pragma unroll 4
  for (int e = 0; e < CE; ++e) {
    float xe = x[e];
    ar += xe * wr[e]; az += xe * wz[e]; an += xe * wn[e];
  }
  ar += bih[j] + bhh[j];
  az += bih[CHID + j] + bhh[CHID + j];
  float r = 1.f / (1.f + expf(-ar));
  float z = 1.f / (1.f + expf(-az));
  float nn = tanhf(an + bih[2 * CHID + j] + r * bhh[2 * CHID + j]);
  h1[(size_t)n * CHID + j] = (1.f - z) * nn;
}

// ---------------------------------------------------------------------------
// Generic 64x64 tiled transpose: in[R][C] -> out[C][R]
// ---------------------------------------------------------------------------
__global__ void trans_kernel(const float* __restrict__ in, float* __restrict__ out,
                             int R, int C) {
  __shared__ float tile[64][65];
  int tj = threadIdx.x & 63, tg = threadIdx.x >> 6;
  int cb = blockIdx.x * 64, rb = blockIdx.y * 64;
  #pragma unroll
  for (int i = 0; i < 16; ++i) {
    int r = tg * 16 + i;
    tile[r][tj] = in[(size_t)(rb + r) * C + cb + tj];
  }
  __syncthreads();
  #pragma unroll
  for (int i = 0; i < 16; ++i) {
    int c2 = tg * 16 + i;
    out[(size_t)(cb + c2) * R + rb + tj] = tile[tj][c2];
  }
}

// ---------------------------------------------------------------------------
// X[:,0] = h1 @ We2^T + be2   (We2T layout [k][e])
// ---------------------------------------------------------------------------
__global__ void x0_kernel(const float* __restrict__ h1, const float* __restrict__ We2T,
                          const float* __restrict__ be2, float* __restrict__ Xout) {
  int et = blockIdx.x, n = blockIdx.y, t = threadIdx.x;
  int el = t & 63, kq = t >> 6;
  __shared__ float hr[1024];
  __shared__ float sred2[4][64];
  for (int idx = t; idx < 1024; idx += 256) hr[idx] = h1[(size_t)n * CHID + idx];
  __syncthreads();
  int e = et * 64 + el;
  float acc = 0.f;
  for (int k = kq * 256; k < kq * 256 + 256; ++k) acc += hr[k] * We2T[(size_t)k * CE + e];
  sred2[kq][el] = acc;
  __syncthreads();
  if (t < 64) {
    float s2 = sred2[0][t] + sred2[1][t] + sred2[2][t] + sred2[3][t] + be2[et * 64 + t];
    Xout[(size_t)(n * CHP) * CE + et * 64 + t] = s2;
  }
}

// ---------------------------------------------------------------------------
// Factorized model weights:
// Wpm[o][e][j]     = sum_a relu( embed_opt[o][a]) * Wm1[j][a*256+e]
// Wpm[o][256+e][j] = sum_a relu(-embed_opt[o][a]) * Wm1[j][a*256+e]
// ---------------------------------------------------------------------------
__global__ void wpm_kernel(const float* __restrict__ Wm1T, const float* __restrict__ eo,
                           float* __restrict__ Wpm) {
  int e = blockIdx.x, jt = blockIdx.y, t = threadIdx.x;
  int j = jt * 256 + t;
  __shared__ float rp[CA * CA], rm[CA * CA];
  for (int idx = t; idx < CA * CA; idx += 256) {
    float v = eo[idx];
    rp[idx] = fmaxf(v, 0.f);
    rm[idx] = fmaxf(-v, 0.f);
  }
  __syncthreads();
  float w[32];
  #pragma unroll
  for (int a = 0; a < 32; ++a) w[a] = Wm1T[(size_t)(a * 256 + e) * CHID + j];
  for (int o = 0; o < 32; ++o) {
    float sp = 0.f, sm = 0.f;
    #pragma unroll
    for (int a = 0; a < 32; ++a) {
      float wa = w[a];
      sp += rp[o * 32 + a] * wa;
      sm += rm[o * 32 + a] * wa;
    }
    Wpm[((size_t)o * 512 + e) * CHID + j] = sp;
    Wpm[((size_t)o * 512 + 256 + e) * CHID + j] = sm;
  }
}

// ---------------------------------------------------------------------------
// Group time-loop rows by option (list order nondeterministic; results aren't)
// ---------------------------------------------------------------------------
__global__ void tllists_kernel(const int* __restrict__ P, int* __restrict__ cnt_tl,
                               int* __restrict__ list_tl) {
  int b = blockIdx.x * 256 + threadIdx.x;
  if (b >= TN) return;
  int a = P[b];
  int slot = atomicAdd(&cnt_tl[a], 1);
  list_tl[a * 256 + slot] = b;
}

// xs_tl[b][k] = relu(+/- prev[b][k&255]),  prev = emb shifted by one t (wrap)
__global__ void xstl_kernel(const float* __restrict__ emb, float* __restrict__ xs) {
  int idx = blockIdx.x * 256 + threadIdx.x;   // < 2048*512
  int b = idx >> 9, k = idx & 511;
  int e = k & 255;
  int bp = (b < CN) ? (b + (CT - 1) * CN) : (b - CN);
  float v = emb[(size_t)bp * CE + e];
  xs[idx] = (k < 256) ? fmaxf(v, 0.f) : fmaxf(-v, 0.f);
}

// ---------------------------------------------------------------------------
// Time-loop factorized model layer 1:
// h[row][j] = relu( sum_{k<512} xs[row][k] * Wpm[o][k][j] + bm1[j] )
// grid (32 o, 8 j-tiles of 128, z row-group start)
// ---------------------------------------------------------------------------
__global__ __launch_bounds__(256) void l1_kernel(
    const float* __restrict__ Wpm, const float* __restrict__ xs,
    const float* __restrict__ bm1, const int* __restrict__ cnt,
    const int* __restrict__ list, int listStride, float* __restrict__ hout) {
  int o = blockIdx.x, jt = blockIdx.y;
  int c = cnt[o];
  if (c <= 0) return;
  __shared__ __align__(16) float sbuf[8192];
  __shared__ int srows[8];
  int t = threadIdx.x;
  int jl = t & 31, kq = t >> 5;
  int jb = jt * 128;
  const float* wb = Wpm + (size_t)o * (512 * CHID) + jb + jl * 4;
  for (int g = blockIdx.z; g * 8 < c; g += gridDim.z) {
    int base = g * 8;
    int nr = min(8, c - base);
    if (t < 8) srows[t] = (t < nr) ? list[o * listStride + base + t] : -1;
    __syncthreads();
    for (int idx = t; idx < 4096; idx += 256) {
      int row = srows[idx >> 9];
      sbuf[idx] = (row >= 0) ? xs[(size_t)row * 512 + (idx & 511)] : 0.f;
    }
    __syncthreads();
    float4 acc[8];
    #pragma unroll
    for (int r = 0; r < 8; ++r) acc[r] = make_float4(0.f, 0.f, 0.f, 0.f);
    int kbase = kq * 64;
    for (int k4 = 0; k4 < 64; k4 += 4) {
      int k = kbase + k4;
      float4 w0 = *(const float4*)(wb + (size_t)(k + 0) * CHID);
      float4 w1 = *(const float4*)(wb + (size_t)(k + 1) * CHID);
      float4 w2 = *(const float4*)(wb + (size_t)(k + 2) * CHID);
      float4 w3 = *(const float4*)(wb + (size_t)(k + 3) * CHID);
      #pragma unroll
      for (int r = 0; r < 8; ++r) {
        float4 xv = *(const float4*)&sbuf[r * 512 + k];
        fma4(acc[r], xv.x, w0); fma4(acc[r], xv.y, w1);
        fma4(acc[r], xv.z, w2); fma4(acc[r], xv.w, w3);
      }
    }
    __syncthreads();
    #pragma unroll
    for (int r = 0; r < 8; ++r)
      *(float4*)&sbuf[(kq * 8 + r) * 128 + jl * 4] = acc[r];
    __syncthreads();
    for (int idx = t; idx < 1024; idx += 256) {
      int r = idx >> 7, jc = idx & 127;
      float s = 0.f;
      #pragma unroll
      for (int q = 0; q < 8; ++q) s += sbuf[(q * 8 + r) * 128 + jc];
      int row = srows[r];
      if (row >= 0)
        hout[(size_t)row * CHID + jb + jc] = fmaxf(s + bm1[jb + jc], 0.f);
    }
    __syncthreads();
  }
}

// ---------------------------------------------------------------------------
// Time-loop layer 2 partials: part[b][kq][e], 8 k-slices of 128
// grid (8 kq, 64 row-groups of 32), 256 thr (= e)
// ---------------------------------------------------------------------------
__global__ __launch_bounds__(256) void l2big_kernel(const float* __restrict__ h,
    const float* __restrict__ Wm2T, float* __restrict__ part) {
  int kq = blockIdx.x, rg = blockIdx.y, t = threadIdx.x;
  int rb = rg * 32, kb = kq * 128;
  __shared__ __align__(16) float hl[4096];
  for (int idx = t; idx < 4096; idx += 256)
    hl[idx] = h[(size_t)(rb + (idx >> 7)) * CHID + kb + (idx & 127)];
  __syncthreads();
  float acc[32];
  #pragma unroll
  for (int r = 0; r < 32; ++r) acc[r] = 0.f;
  for (int kk = 0; kk < 128; kk += 4) {
    float w0 = Wm2T[(size_t)(kb + kk + 0) * CE + t];
    float w1 = Wm2T[(size_t)(kb + kk + 1) * CE + t];
    float w2 = Wm2T[(size_t)(kb + kk + 2) * CE + t];
    float w3 = Wm2T[(size_t)(kb + kk + 3) * CE + t];
    #pragma unroll
    for (int r = 0; r < 32; ++r) {
      float4 hv = *(const float4*)&hl[r * 128 + kk];
      acc[r] += hv.x * w0 + hv.y * w1 + hv.z * w2 + hv.w * w3;
    }
  }
  #pragma unroll
  for (int r = 0; r < 32; ++r)
    part[((size_t)(rb + r) * 8 + kq) * CE + t] = acc[r];
}

// model_loss = (sum(partials)+bm2 - emb)^2
__global__ void ml_kernel(const float* __restrict__ part, const float* __restrict__ bm2,
                          const float* __restrict__ emb, float* __restrict__ ML) {
  int idx = blockIdx.x * 256 + threadIdx.x;   // < 2048*256
  int b = idx >> 8, e = idx & 255;
  float outv = bm2[e];
  #pragma unroll
  for (int q = 0; q < 8; ++q) outv += part[((size_t)b * 8 + q) * CE + e];
  float d = outv - emb[idx];
  ML[idx] = d * d;
}

// ---------------------------------------------------------------------------
// fin phase (blocks 0..63, n = bid): epilogue of step s-1 + decision of step s.
// Per-n state in block LDS. Cross-block data via LLC-bypass atomics (gld/gst)
// -> NO agent fences anywhere in the steady-state loop. s==CS: epilogue only.
// ---------------------------------------------------------------------------
__device__ __forceinline__ void fin_phase(
    int s, int n, int t,
    const int* __restrict__ P, const float* __restrict__ Wsg,
    const float* __restrict__ bsg, const float* __restrict__ Wcg,
    const float* __restrict__ bcg, const float* __restrict__ bm2,
    float* __restrict__ part_db, float* __restrict__ Xout,
    float* __restrict__ SLout, float* __restrict__ VALout,
    float* __restrict__ PAout, float* __restrict__ xsbuf,
    int* __restrict__ cnt, int* __restrict__ lists,
    int* __restrict__ row_done, int* __restrict__ dec_done,
    float* sx, float* sred, float* svals, float* sxtra, int* sint,
    float* logits_s, float* Xlds) {
  // Read-only prefetch (stays L2-warm now that no fences invalidate it);
  // latency hides under the dependency wait.
  float wsv = 0.f, bm2v = 0.f, bcv = 0.f, bsv = bsg[0];
  float wcv[32];
  int c2 = t >> 3, g = t & 7;
  if (t < 256) {
    wsv = Wsg[t]; bm2v = bm2[t];
    #pragma unroll
    for (int i = 0; i < 32; ++i) wcv[i] = Wcg[c2 * CE + g * 32 + i];
  }
  if (t < CA) bcv = bcg[t];

  if (s > 0) {
    int push = sint[SI_PUSH];
    if (push) {
      if (t == 0) {
        int* rd = &row_done[(s - 1) * CN + n];
        while (__hip_atomic_load(rd, __ATOMIC_RELAXED, __HIP_MEMORY_SCOPE_AGENT) < 8)
          __builtin_amdgcn_s_sleep(1);
      }
      __syncthreads();
      int Iup = sint[SI_IUP];
      if (t < 256) {
        float* pb = part_db + (((size_t)((s - 1) & 1) * CN + n) * 8) * CE + t;
        float outv = bm2v;
        #pragma unroll
        for (int q = 0; q < 8; ++q) outv += gld(pb + (size_t)q * CE);
        Xlds[Iup * CE + t] = outv;
        Xout[((size_t)(n * CHP) + Iup) * CE + t] = outv;
        sx[t] = outv;
      }
      if (t == 0) sint[SI_I] = Iup;
    } else {
      int I = sint[SI_I];
      int Inew = (I - 1 > 0) ? I - 1 : 0;
      if (t < 256) sx[t] = Xlds[Inew * CE + t];
      if (t == 0) sint[SI_I] = Inew;
    }
    if (s == CS) return;  // final epilogue only (uniform)
  } else {
    if (t < 256) sx[t] = Xlds[t];
    if (t == 0) sint[SI_I] = 0;
  }
  __syncthreads();
  int I = sint[SI_I];
  if (t < 256) {
    float xv = sx[t];
    float xa = fmaxf(xv, 0.f);
    gst(&xsbuf[n * 512 + t], xa);
    gst(&xsbuf[n * 512 + 256 + t], fmaxf(-xv, 0.f));
    sred[t] = xa * wsv;
  }
  __syncthreads();
  #pragma unroll
  for (int off = 128; off > 0; off >>= 1) {
    if (t < off) sred[t] += sred[t + off];
    __syncthreads();
  }
  if (t == 0) { sxtra[0] = sred[0] + bsv; sint[SI_FLAG] = 1; }
  if (t < 256) {
    float pv = 0.f;
    #pragma unroll 4
    for (int i = 0; i < 32; ++i)
      pv += fmaxf(sx[g * 32 + i], 0.f) * wcv[i];
    pv += __shfl_down(pv, 4, 8);
    pv += __shfl_down(pv, 2, 8);
    pv += __shfl_down(pv, 1, 8);
    if (g == 0) svals[c2] = pv + bcv;
  }
  __syncthreads();
  if (t < CA && logits_s[t] != 0.f) sint[SI_FLAG] = 0;
  __syncthreads();
  int a = P[s * CN + n];
  if (t < CA) {
    float v = svals[t];
    float slv = sint[SI_FLAG] ? sxtra[0] * v : logits_s[t];
    SLout[(size_t)(s * CN + n) * CA + t] = slv;
    logits_s[t] = slv - (t == a ? 1e8f : 0.f);
    if (t == a) {
      VALout[s * CN + n] = slv;
      int pn = (v > 0.f) ? 1 : 0;
      sint[SI_PUSH] = pn;
      PAout[n * CHP + I] = (float)a;
      sint[SI_IUP] = (I + 1 < CHP - 1) ? I + 1 : CHP - 1;
      if (pn) {
        int slot = atomicAdd(&cnt[s * CA + a], 1);
        gsti(&lists[(s * CA + a) * CN + slot], n);
      }
    }
  }
  __syncthreads();   // drains every thread's stores (vmcnt before s_barrier)
  if (t == 0) {
    waitst();
    __hip_atomic_fetch_add(&dec_done[s], 1, __ATOMIC_RELAXED, __HIP_MEMORY_SCOPE_AGENT);
  }
  __syncthreads();
}

// ---------------------------------------------------------------------------
// Persistent planning kernel: 256 blocks x 512 threads (1 block/CU, LDS-forced).
// Round-7 post-mortem: VGPR_Count pinned at 124 through launch_bounds(512,1),
// waves_per_eu(2,2) AND scalar asm pins -> register-residency for W is
// unachievable on this toolchain (allocator spills/remats regardless). The
// REAL cost was the agent fences: each acquire invalidates / each release
// writes back the XCD L2 (~300-600/step chip-wide) evicting all read-only
// state. This version has ZERO steady-state fences: cross-block data goes
// through LLC-bypass relaxed atomics (gld/gst), flags via relaxed atomic adds
// ordered by __syncthreads' vmcnt drain. W re-reads (spilled or remat'd) now
// hit warm L2. Phase A computes 4 rows per W pass (4x less W traffic).
// ---------------------------------------------------------------------------
#define W_EACH(M) M(0) M(1) M(2) M(3) M(4) M(5) M(6) M(7) M(8) M(9) M(10) \
  M(11) M(12) M(13) M(14) M(15) M(16) M(17) M(18) M(19) M(20) M(21) M(22) \
  M(23) M(24) M(25) M(26) M(27) M(28) M(29) M(30) M(31)
#define WLD(i) float4 W##i = *(const float4*)(wsrc + (size_t)(i) * CHID);
#define WFM4(i) { \
  float x0_ = xk0[i], x1_ = xk1[i], x2_ = xk2[i], x3_ = xk3[i]; \
  ac0.x = fmaf(x0_, W##i.x, ac0.x); ac0.y = fmaf(x0_, W##i.y, ac0.y); \
  ac0.z = fmaf(x0_, W##i.z, ac0.z); ac0.w = fmaf(x0_, W##i.w, ac0.w); \
  ac1.x = fmaf(x1_, W##i.x, ac1.x); ac1.y = fmaf(x1_, W##i.y, ac1.y); \
  ac1.z = fmaf(x1_, W##i.z, ac1.z); ac1.w = fmaf(x1_, W##i.w, ac1.w); \
  ac2.x = fmaf(x2_, W##i.x, ac2.x); ac2.y = fmaf(x2_, W##i.y, ac2.y); \
  ac2.z = fmaf(x2_, W##i.z, ac2.z); ac2.w = fmaf(x2_, W##i.w, ac2.w); \
  ac3.x = fmaf(x3_, W##i.x, ac3.x); ac3.y = fmaf(x3_, W##i.y, ac3.y); \
  ac3.z = fmaf(x3_, W##i.z, ac3.z); ac3.w = fmaf(x3_, W##i.w, ac3.w); }

// Per-row reduce + layer-2 + part store. rr/nb2 are block-uniform -> the
// __syncthreads inside the guarded body are convergent.
#define ROW_EPI(rr, ar) \
  if (rr < nb2) { \
    *(float4*)&red[kq * 128 + jl * 4] = ar; \
    __syncthreads(); \
    if (t < 128) { \
      float s1 = 0.f; \
      _Pragma("unroll") \
      for (int q = 0; q < 16; ++q) s1 += red[q * 128 + t]; \
      sh[t] = fmaxf(s1 + bm1s[t], 0.f); \
    } \
    __syncthreads(); \
    if (t < 256) { \
      float dot2 = 0.f; \
      _Pragma("unroll 16") \
      for (int jj = 0; jj < 64; ++jj) { \
        float2 hv = *(const float2*)&sh[jj * 2]; \
        float2 wv = *(const float2*)&wm2s[t * 130 + jj * 2]; \
        dot2 = fmaf(hv.x, wv.x, fmaf(hv.y, wv.y, dot2)); \
      } \
      gst(&part_db[(((size_t)(s & 1) * CN + srows[rr]) * 8 + jt) * CE + t], dot2); \
    } \
    __syncthreads(); \
  }

__global__ void
__attribute__((amdgpu_flat_work_group_size(512, 512), amdgpu_waves_per_eu(2, 2)))
plan_kernel(
    const float* __restrict__ Wpm, const float* __restrict__ Wm2T,
    const float* __restrict__ bm1g, const int* __restrict__ P,
    const float* Wsg, const float* bsg, const float* Wcg, const float* bcg,
    const float* bm2, float* Xout, float* SLout, float* VALout, float* PAout,
    float* xsbuf, int* cnt, int* lists, int* row_done, int* dec_done,
    float* part_db) {
  extern __shared__ float smem[];
  float* wm2s    = smem;                  // [256 e][130 pad] = 33280
  float* bm1s    = wm2s + 33280;          // 128
  float* red     = bm1s + 128;            // 16*128 = 2048
  float* sh      = red + 2048;            // 128
  float* sxs     = sh + 128;              // 4*512 = 2048
  float* sx      = sxs + 2048;            // 256
  float* sred    = sx + 256;              // 256
  float* svals   = sred + 256;            // 32
  float* sxtra   = svals + 32;            // 4
  int*   sint    = (int*)(sxtra + 4);     // 8
  int*   srows   = sint + 8;              // 4
  int*   rowsAll = srows + 4;             // 64
  float* logits_s= (float*)(rowsAll + 64);// 32
  float* Xlds    = logits_s + 32;         // 2048
  // total 40336 floats = 161344 B <= 160 KiB

  int bid = blockIdx.x, t = threadIdx.x;
  int o = bid >> 3, jt = bid & 7;
  int jl = t & 31, kq = t >> 5;           // kq in [0,16): 32 k each
  int jb = jt * 128;

  // --- prologue: weight slice + LDS state ---
  const float* wsrc = Wpm + ((size_t)o * 512 + (size_t)kq * 32) * CHID + jb + jl * 4;
  W_EACH(WLD)
  for (int idx = t; idx < 128 * 256; idx += 512) {
    int e = idx & 255, j = idx >> 8;
    wm2s[e * 130 + j] = Wm2T[(size_t)(jb + j) * CE + e];
  }
  if (t < 128) bm1s[t] = bm1g[jb + t];
  if (bid < CN) {
    for (int idx = t; idx < CHP * CE; idx += 512)
      Xlds[idx] = Xout[(size_t)bid * (CHP * CE) + idx];
    if (t < 32) logits_s[t] = 0.f;
    if (t < 8) sint[t] = 0;
  }
  __syncthreads();

  if (bid < CN)
    fin_phase(0, bid, t, P, Wsg, bsg, Wcg, bcg, bm2, part_db, Xout, SLout,
              VALout, PAout, xsbuf, cnt, lists, row_done, dec_done,
              sx, sred, svals, sxtra, sint, logits_s, Xlds);

  for (int s = 0; s < CS; ++s) {
    // --- phase A: wait decisions, run l1+l2 for this option's pushed rows ---
    if (t == 0) {
      while (__hip_atomic_load(&dec_done[s], __ATOMIC_RELAXED,
                               __HIP_MEMORY_SCOPE_AGENT) < CN)
        __builtin_amdgcn_s_sleep(2);
    }
    __syncthreads();
    int c = gldi(&cnt[s * CA + o]);
    for (int base = 0; base < c; base += 4) {
      int nb2 = min(4, c - base);
      if (t < 4) srows[t] = (t < nb2) ? gldi(&lists[(s * CA + o) * CN + base + t]) : -1;
      __syncthreads();
      for (int idx = t; idx < 2048; idx += 512) {
        int row = srows[idx >> 9];
        sxs[idx] = (row >= 0) ? gld(&xsbuf[row * 512 + (idx & 511)]) : 0.f;
      }
      if (t < nb2) rowsAll[base + t] = srows[t];
      __syncthreads();
      // one W pass computes up to 4 rows (4x less W traffic than per-row)
      float4 ac0, ac1, ac2, ac3;
      ac0.x = ac0.y = ac0.z = ac0.w = 0.f;
      ac1 = ac0; ac2 = ac0; ac3 = ac0;
      const float* xk0 = sxs + 0 * 512 + kq * 32;
      const float* xk1 = sxs + 1 * 512 + kq * 32;
      const float* xk2 = sxs + 2 * 512 + kq * 32;
      const float* xk3 = sxs + 3 * 512 + kq * 32;
      W_EACH(WFM4)
      ROW_EPI(0, ac0)
      ROW_EPI(1, ac1)
      ROW_EPI(2, ac2)
      ROW_EPI(3, ac3)
    }
    __syncthreads();   // drains part stores (vmcnt before s_barrier)
    if (t == 0 && c > 0) {
      waitst();
      for (int r = 0; r < c; ++r)
        __hip_atomic_fetch_add(&row_done[s * CN + rowsAll[r]], 1,
                               __ATOMIC_RELAXED, __HIP_MEMORY_SCOPE_AGENT);
    }
    // --- fin: epilogue(s) + decision(s+1) ---
    if (bid < CN)
      fin_phase(s + 1, bid, t, P, Wsg, bsg, Wcg, bcg, bm2, part_db, Xout, SLout,
                VALout, PAout, xsbuf, cnt, lists, row_done, dec_done,
                sx, sred, svals, sxtra, sint, logits_s, Xlds);
  }
}

// ---------------------------------------------------------------------------
// embed_loss
// ---------------------------------------------------------------------------
__global__ void el_kernel(const float* __restrict__ emb, const float* __restrict__ Xout,
                          const float* __restrict__ Ws, const float* __restrict__ bsp,
                          float* __restrict__ EL) {
  int tn = blockIdx.x;
  int n = tn & 63;
  int t = threadIdx.x, h = t >> 5, l = t & 31;
  const float* er = emb + (size_t)tn * CE;
  const float* xr = Xout + ((size_t)(n * CHP) + h) * CE;
  float pd = 0.f, px = 0.f, pe = 0.f, ps = 0.f;
  #pragma unroll
  for (int i = 0; i < 8; ++i) {
    int e = l * 8 + i;
    float ev = er[e], xv2 = xr[e];
    pd += ev * xv2; px += xv2 * xv2; pe += ev * ev; ps += fmaxf(ev, 0.f) * Ws[e];
  }
  #pragma unroll
  for (int off = 16; off > 0; off >>= 1) {
    pd += __shfl_down(pd, off, 32);
    px += __shfl_down(px, off, 32);
    pe += __shfl_down(pe, off, 32);
    ps += __shfl_down(ps, off, 32);
  }
  __shared__ float sdot[8], snx[8];
  __shared__ float sne, ssh;
  if (l == 0) {
    sdot[h] = pd;
    snx[h] = sqrtf(px);
    if (h == 0) { sne = sqrtf(pe); ssh = ps + bsp[0]; }
  }
  __syncthreads();
  if (t == 0) {
    const float eps = 1e-8f;
    float y[8];
    float m = -1e30f;
    #pragma unroll
    for (int hh = 0; hh < 8; ++hh) {
      float cs = sdot[hh] / ((sne + eps) * (snx[hh] + eps));
      y[hh] = ssh * cs;
      m = fmaxf(m, y[hh]);
    }
    float sum = 0.f;
    #pragma unroll
    for (int hh = 0; hh < 8; ++hh) sum += expf(y[hh] - m);
    float lse = logf(sum);
    float el = 0.f;
    #pragma unroll
    for (int hh = 0; hh < 8; ++hh) {
      float lp = y[hh] - m - lse;
      el += expf(lp) * lp;
    }
    EL[tn] = el;
  }
}

// ---------------------------------------------------------------------------
extern "C" void kernel_launch(void* const* d_in, const int* in_sizes, int n_in,
                              void* d_out, int out_size, void* d_ws, size_t ws_size,
                              hipStream_t stream) {
  (void)in_sizes; (void)n_in; (void)out_size; (void)ws_size;
  const int*   obs    = (const int*)d_in[0];
  const int*   P      = (const int*)d_in[1];
  const float* embed1 = (const float*)d_in[2];
  const float* Wih    = (const float*)d_in[3];
  // d_in[4] = Whh: provably unused (h0 = 0 and only Hs[0] is consumed)
  const float* bih    = (const float*)d_in[5];
  const float* bhh    = (const float*)d_in[6];
  const float* We2    = (const float*)d_in[7];
  const float* be2    = (const float*)d_in[8];
  const float* Ws     = (const float*)d_in[9];
  const float* bs     = (const float*)d_in[10];
  const float* Wc     = (const float*)d_in[11];
  const float* bc     = (const float*)d_in[12];
  const float* Wm1    = (const float*)d_in[13];
  const float* bm1    = (const float*)d_in[14];
  const float* Wm2    = (const float*)d_in[15];
  const float* bm2    = (const float*)d_in[16];
  const float* eo     = (const float*)d_in[17];
  float* out = (float*)d_out;
  char*  ws  = (char*)d_ws;

  float* emb    = (float*)(ws + B_EMB);
  float* h1     = (float*)(ws + B_H1);
  float* xsp    = (float*)(ws + B_XS);
  float* part_db= (float*)(ws + B_PART);
  int*   cntp   = (int*)(ws + B_CNT);
  int*   decd   = (int*)(ws + B_DEC);
  int*   rowd   = (int*)(ws + B_ROW);
  int*   listp  = (int*)(ws + B_LISTS);
  int*   cnttl  = (int*)(ws + B_CNTTL);
  int*   listtl = (int*)(ws + B_LISTTL);
  float* we2t   = (float*)(ws + B_WE2T);
  float* wm1t   = (float*)(ws + B_WM1T);
  float* xstl   = (float*)(ws + B_XSTL);
  float* hbig   = (float*)(ws + B_HBIG);
  float* parttl = (float*)(ws + B_PARTTL);
  float* wm2t   = (float*)(ws + B_WM2T);
  float* wpm    = (float*)(ws + B_WPM);

  dim3 thr(256);
  init_kernel<<<dim3(514), thr, 0, stream>>>(out, cntp, decd, rowd, cnttl);
  emb_kernel<<<dim3(256), thr, 0, stream>>>(obs, embed1, emb);
  h1_kernel<<<dim3(256), thr, 0, stream>>>(emb, Wih, bih, bhh, h1);
  trans_kernel<<<dim3(16, 4), thr, 0, stream>>>(We2, we2t, CE, CHID);        // We2T
  x0_kernel<<<dim3(4, 64), thr, 0, stream>>>(h1, we2t, be2, out + O_X);
  trans_kernel<<<dim3(128, 16), thr, 0, stream>>>(Wm1, wm1t, CHID, CA * CE); // Wm1T
  wpm_kernel<<<dim3(256, 4), thr, 0, stream>>>(wm1t, eo, wpm);
  trans_kernel<<<dim3(16, 4), thr, 0, stream>>>(Wm2, wm2t, CE, CHID);        // Wm2T
  tllists_kernel<<<dim3(8), thr, 0, stream>>>(P, cnttl, listtl);
  xstl_kernel<<<dim3(4096), thr, 0, stream>>>(emb, xstl);
  // time-loop model (factorized, f32)
  l1_kernel<<<dim3(32, 8, 8), thr, 0, stream>>>(wpm, xstl, bm1, cnttl, listtl, 256, hbig);
  l2big_kernel<<<dim3(8, 64), thr, 0, stream>>>(hbig, wm2t, parttl);
  ml_kernel<<<dim3(2048), thr, 0, stream>>>(parttl, bm2, emb, out + O_ML);
  // planning loop: persistent kernel, fence-free LLC-coherent handoffs
  constexpr size_t PLAN_SMEM = 40336 * sizeof(float);  // 161344 B <= 160 KiB
  plan_kernel<<<dim3(256), dim3(512), PLAN_SMEM, stream>>>(
      wpm, wm2t, bm1, P, Ws, bs, Wc, bc, bm2,
      out + O_X, out + O_SL, out + O_VAL, out + O_PA,
      xsp, cntp, listp, rowd, decd, part_db);
  el_kernel<<<dim3(2048), thr, 0, stream>>>(emb, out + O_X, Ws, bs, out + O_EL);
}

// Round 9
// 695.265 us; speedup vs baseline: 1.3214x; 1.2657x over previous
//
#include <hip/hip_runtime.h>

// ---------------------------------------------------------------------------
// Problem constants
// ---------------------------------------------------------------------------
constexpr int CT = 32;      // T
constexpr int CN = 64;      // N
constexpr int CE = 256;     // E = DOBS*V
constexpr int CHID = 1024;
constexpr int CA = 32;      // num options
constexpr int CS = 32;      // planning steps
constexpr int CHP = 8;      // planning horizon
constexpr int TN = CT * CN; // 2048

// d_out float offsets (return order: search_logits, planned_actions, X, value,
// model_loss, embed_loss)
constexpr size_t O_SL  = 0;        // 32*64*32 = 65536
constexpr size_t O_PA  = 65536;    // 64*8     = 512
constexpr size_t O_X   = 66048;    // 64*8*256 = 131072
constexpr size_t O_VAL = 197120;   // 32*64    = 2048
constexpr size_t O_ML  = 199168;   // 32*64*256= 524288
constexpr size_t O_EL  = 723456;   // 32*64    = 2048

// ws byte offsets (~100 MB total)
constexpr size_t B_EMB    = 0;                           // 2 MB   [2048][256] f32
constexpr size_t B_H1     = 2u * 1024 * 1024;            // 256 KB [64][1024]
constexpr size_t B_PART   = B_H1 + 512 * 1024;           // 512 KB [2 par][64][4][256]
// control block at 3.5 MB
constexpr size_t B_FLG    = 3584u * 1024;                // 64*4*16 ints = 16 KB
constexpr size_t B_CNTTL  = B_FLG + 32 * 1024;           // 32 ints
constexpr size_t B_LISTTL = B_CNTTL + 4 * 1024;          // 32 KB [32][256]
// 32MB+ multi-phase region: We2T (early) -> Wm1T (mid) -> xstl/hbig/parttl/Wm2T
constexpr size_t B_R32    = 4u * 1024 * 1024;
constexpr size_t B_WE2T   = B_R32;                       // 1 MB  (dead after x0)
constexpr size_t B_WM1T   = B_R32;                       // 32 MB (dead after wpm)
constexpr size_t B_XSTL   = B_R32;                       // 4 MB  [2048][512]
constexpr size_t B_HBIG   = B_R32 + 4u * 1024 * 1024;    // 8 MB  [2048][1024]
constexpr size_t B_PARTTL = B_R32 + 12u * 1024 * 1024;   // 16 MB [2048][8][256]
constexpr size_t B_WM2T   = B_R32 + 28u * 1024 * 1024;   // 1 MB  [1024][256]
constexpr size_t B_WPM    = B_R32 + 32u * 1024 * 1024;   // 64 MB [32][512][1024]

// LDS scalar-state indices
constexpr int SI_FLAG = 0, SI_I = 1, SI_PUSH = 2, SI_IUP = 3;

__device__ __forceinline__ void fma4(float4& a, float s, const float4& w) {
  a.x = fmaf(s, w.x, a.x); a.y = fmaf(s, w.y, a.y);
  a.z = fmaf(s, w.z, a.z); a.w = fmaf(s, w.w, a.w);
}

// LLC-coherent relaxed accessors (cross-block data; no fences needed: producer
// ordering via __syncthreads' vmcnt drain before s_barrier)
__device__ __forceinline__ float gld(const float* p) {
  return __hip_atomic_load(p, __ATOMIC_RELAXED, __HIP_MEMORY_SCOPE_AGENT);
}
__device__ __forceinline__ void gst(float* p, float v) {
  __hip_atomic_store(p, v, __ATOMIC_RELAXED, __HIP_MEMORY_SCOPE_AGENT);
}
__device__ __forceinline__ int gldi(const int* p) {
  return __hip_atomic_load(p, __ATOMIC_RELAXED, __HIP_MEMORY_SCOPE_AGENT);
}
__device__ __forceinline__ void gsti(int* p, int v) {
  __hip_atomic_store(p, v, __ATOMIC_RELAXED, __HIP_MEMORY_SCOPE_AGENT);
}
__device__ __forceinline__ void waitst() {
  asm volatile("s_waitcnt vmcnt(0)" ::: "memory");
}

// ---------------------------------------------------------------------------
// init: zero PA+X span of d_out, per-chain flags, time-loop counters
// ---------------------------------------------------------------------------
__global__ void init_kernel(float* __restrict__ out, int* __restrict__ flg,
                            int* __restrict__ cnt_tl) {
  int idx = blockIdx.x * 256 + threadIdx.x;
  if (idx < 131584) out[O_PA + idx] = 0.f;  // PA (512) + X (131072) contiguous
  if (idx < CN * 4 * 16) flg[idx] = 0;
  if (idx < CA) cnt_tl[idx] = 0;
}

// ---------------------------------------------------------------------------
// emb[t][n][e] = embed1[obs[t][n][e>>4]][e&15]
// ---------------------------------------------------------------------------
__global__ void emb_kernel(const int* __restrict__ obs, const float* __restrict__ embed1,
                           float* __restrict__ emb) {
  int idx = blockIdx.x * 256 + threadIdx.x;
  int b = idx >> 5, k8 = idx & 31;
  int e0 = k8 * 8;
  int d = e0 >> 4;
  int o = obs[b * 16 + d];
  const float* src = embed1 + o * 16 + (e0 & 15);
  float4 v0 = *(const float4*)src;
  float4 v1 = *(const float4*)(src + 4);
  float* dst = emb + (size_t)b * CE + e0;
  *(float4*)dst = v0;
  *(float4*)(dst + 4) = v1;
}

// ---------------------------------------------------------------------------
// One GRU step with h0 = 0 (only Hs[0] used downstream; Whh provably unused)
// ---------------------------------------------------------------------------
__global__ void h1_kernel(const float* __restrict__ emb, const float* __restrict__ Wih,
                          const float* __restrict__ bih, const float* __restrict__ bhh,
                          float* __restrict__ h1) {
  int t = threadIdx.x, bid = blockIdx.x;   // 256 blocks of (64n x 4j)
  int n = t & 63, j = bid * 4 + (t >> 6);
  const float* x = emb + (size_t)n * CE;   // emb[0] rows
  const float* wr = Wih + (size_t)j * CE;
  const float* wz = Wih + (size_t)(CHID + j) * CE;
  const float* wn = Wih + (size_t)(2 * CHID + j) * CE;
  float ar = 0.f, az = 0.f, an = 0.f;
  #pragma unroll 4
  for (int e = 0; e < CE; ++e) {
    float xe = x[e];
    ar += xe * wr[e]; az += xe * wz[e]; an += xe * wn[e];
  }
  ar += bih[j] + bhh[j];
  az += bih[CHID + j] + bhh[CHID + j];
  float r = 1.f / (1.f + expf(-ar));
  float z = 1.f / (1.f + expf(-az));
  float nn = tanhf(an + bih[2 * CHID + j] + r * bhh[2 * CHID + j]);
  h1[(size_t)n * CHID + j] = (1.f - z) * nn;
}

// ---------------------------------------------------------------------------
// Generic 64x64 tiled transpose: in[R][C] -> out[C][R]
// ---------------------------------------------------------------------------
__global__ void trans_kernel(const float* __restrict__ in, float* __restrict__ out,
                             int R, int C) {
  __shared__ float tile[64][65];
  int tj = threadIdx.x & 63, tg = threadIdx.x >> 6;
  int cb = blockIdx.x * 64, rb = blockIdx.y * 64;
  #pragma unroll
  for (int i = 0; i < 16; ++i) {
    int r = tg * 16 + i;
    tile[r][tj] = in[(size_t)(rb + r) * C + cb + tj];
  }
  __syncthreads();
  #pragma unroll
  for (int i = 0; i < 16; ++i) {
    int c2 = tg * 16 + i;
    out[(size_t)(cb + c2) * R + rb + tj] = tile[tj][c2];
  }
}

// ---------------------------------------------------------------------------
// X[:,0] = h1 @ We2^T + be2   (We2T layout [k][e])
// ---------------------------------------------------------------------------
__global__ void x0_kernel(const float* __restrict__ h1, const float* __restrict__ We2T,
                          const float* __restrict__ be2, float* __restrict__ Xout) {
  int et = blockIdx.x, n = blockIdx.y, t = threadIdx.x;
  int el = t & 63, kq = t >> 6;
  __shared__ float hr[1024];
  __shared__ float sred2[4][64];
  for (int idx = t; idx < 1024; idx += 256) hr[idx] = h1[(size_t)n * CHID + idx];
  __syncthreads();
  int e = et * 64 + el;
  float acc = 0.f;
  for (int k = kq * 256; k < kq * 256 + 256; ++k) acc += hr[k] * We2T[(size_t)k * CE + e];
  sred2[kq][el] = acc;
  __syncthreads();
  if (t < 64) {
    float s2 = sred2[0][t] + sred2[1][t] + sred2[2][t] + sred2[3][t] + be2[et * 64 + t];
    Xout[(size_t)(n * CHP) * CE + et * 64 + t] = s2;
  }
}

// ---------------------------------------------------------------------------
// Factorized model weights:
// Wpm[o][e][j]     = sum_a relu( embed_opt[o][a]) * Wm1[j][a*256+e]
// Wpm[o][256+e][j] = sum_a relu(-embed_opt[o][a]) * Wm1[j][a*256+e]
// ---------------------------------------------------------------------------
__global__ void wpm_kernel(const float* __restrict__ Wm1T, const float* __restrict__ eo,
                           float* __restrict__ Wpm) {
  int e = blockIdx.x, jt = blockIdx.y, t = threadIdx.x;
  int j = jt * 256 + t;
  __shared__ float rp[CA * CA], rm[CA * CA];
  for (int idx = t; idx < CA * CA; idx += 256) {
    float v = eo[idx];
    rp[idx] = fmaxf(v, 0.f);
    rm[idx] = fmaxf(-v, 0.f);
  }
  __syncthreads();
  float w[32];
  #pragma unroll
  for (int a = 0; a < 32; ++a) w[a] = Wm1T[(size_t)(a * 256 + e) * CHID + j];
  for (int o = 0; o < 32; ++o) {
    float sp = 0.f, sm = 0.f;
    #pragma unroll
    for (int a = 0; a < 32; ++a) {
      float wa = w[a];
      sp += rp[o * 32 + a] * wa;
      sm += rm[o * 32 + a] * wa;
    }
    Wpm[((size_t)o * 512 + e) * CHID + j] = sp;
    Wpm[((size_t)o * 512 + 256 + e) * CHID + j] = sm;
  }
}

// ---------------------------------------------------------------------------
// Group time-loop rows by option (list order nondeterministic; results aren't)
// ---------------------------------------------------------------------------
__global__ void tllists_kernel(const int* __restrict__ P, int* __restrict__ cnt_tl,
                               int* __restrict__ list_tl) {
  int b = blockIdx.x * 256 + threadIdx.x;
  if (b >= TN) return;
  int a = P[b];
  int slot = atomicAdd(&cnt_tl[a], 1);
  list_tl[a * 256 + slot] = b;
}

// xs_tl[b][k] = relu(+/- prev[b][k&255]),  prev = emb shifted by one t (wrap)
__global__ void xstl_kernel(const float* __restrict__ emb, float* __restrict__ xs) {
  int idx = blockIdx.x * 256 + threadIdx.x;   // < 2048*512
  int b = idx >> 9, k = idx & 511;
  int e = k & 255;
  int bp = (b < CN) ? (b + (CT - 1) * CN) : (b - CN);
  float v = emb[(size_t)bp * CE + e];
  xs[idx] = (k < 256) ? fmaxf(v, 0.f) : fmaxf(-v, 0.f);
}

// ---------------------------------------------------------------------------
// Time-loop factorized model layer 1:
// h[row][j] = relu( sum_{k<512} xs[row][k] * Wpm[o][k][j] + bm1[j] )
// grid (32 o, 8 j-tiles of 128, z row-group start)
// ---------------------------------------------------------------------------
__global__ __launch_bounds__(256) void l1_kernel(
    const float* __restrict__ Wpm, const float* __restrict__ xs,
    const float* __restrict__ bm1, const int* __restrict__ cnt,
    const int* __restrict__ list, int listStride, float* __restrict__ hout) {
  int o = blockIdx.x, jt = blockIdx.y;
  int c = cnt[o];
  if (c <= 0) return;
  __shared__ __align__(16) float sbuf[8192];
  __shared__ int srows[8];
  int t = threadIdx.x;
  int jl = t & 31, kq = t >> 5;
  int jb = jt * 128;
  const float* wb = Wpm + (size_t)o * (512 * CHID) + jb + jl * 4;
  for (int g = blockIdx.z; g * 8 < c; g += gridDim.z) {
    int base = g * 8;
    int nr = min(8, c - base);
    if (t < 8) srows[t] = (t < nr) ? list[o * listStride + base + t] : -1;
    __syncthreads();
    for (int idx = t; idx < 4096; idx += 256) {
      int row = srows[idx >> 9];
      sbuf[idx] = (row >= 0) ? xs[(size_t)row * 512 + (idx & 511)] : 0.f;
    }
    __syncthreads();
    float4 acc[8];
    #pragma unroll
    for (int r = 0; r < 8; ++r) acc[r] = make_float4(0.f, 0.f, 0.f, 0.f);
    int kbase = kq * 64;
    for (int k4 = 0; k4 < 64; k4 += 4) {
      int k = kbase + k4;
      float4 w0 = *(const float4*)(wb + (size_t)(k + 0) * CHID);
      float4 w1 = *(const float4*)(wb + (size_t)(k + 1) * CHID);
      float4 w2 = *(const float4*)(wb + (size_t)(k + 2) * CHID);
      float4 w3 = *(const float4*)(wb + (size_t)(k + 3) * CHID);
      #pragma unroll
      for (int r = 0; r < 8; ++r) {
        float4 xv = *(const float4*)&sbuf[r * 512 + k];
        fma4(acc[r], xv.x, w0); fma4(acc[r], xv.y, w1);
        fma4(acc[r], xv.z, w2); fma4(acc[r], xv.w, w3);
      }
    }
    __syncthreads();
    #pragma unroll
    for (int r = 0; r < 8; ++r)
      *(float4*)&sbuf[(kq * 8 + r) * 128 + jl * 4] = acc[r];
    __syncthreads();
    for (int idx = t; idx < 1024; idx += 256) {
      int r = idx >> 7, jc = idx & 127;
      float s = 0.f;
      #pragma unroll
      for (int q = 0; q < 8; ++q) s += sbuf[(q * 8 + r) * 128 + jc];
      int row = srows[r];
      if (row >= 0)
        hout[(size_t)row * CHID + jb + jc] = fmaxf(s + bm1[jb + jc], 0.f);
    }
    __syncthreads();
  }
}

// ---------------------------------------------------------------------------
// Time-loop layer 2 partials: part[b][kq][e], 8 k-slices of 128
// grid (8 kq, 64 row-groups of 32), 256 thr (= e)
// ---------------------------------------------------------------------------
__global__ __launch_bounds__(256) void l2big_kernel(const float* __restrict__ h,
    const float* __restrict__ Wm2T, float* __restrict__ part) {
  int kq = blockIdx.x, rg = blockIdx.y, t = threadIdx.x;
  int rb = rg * 32, kb = kq * 128;
  __shared__ __align__(16) float hl[4096];
  for (int idx = t; idx < 4096; idx += 256)
    hl[idx] = h[(size_t)(rb + (idx >> 7)) * CHID + kb + (idx & 127)];
  __syncthreads();
  float acc[32];
  #pragma unroll
  for (int r = 0; r < 32; ++r) acc[r] = 0.f;
  for (int kk = 0; kk < 128; kk += 4) {
    float w0 = Wm2T[(size_t)(kb + kk + 0) * CE + t];
    float w1 = Wm2T[(size_t)(kb + kk + 1) * CE + t];
    float w2 = Wm2T[(size_t)(kb + kk + 2) * CE + t];
    float w3 = Wm2T[(size_t)(kb + kk + 3) * CE + t];
    #pragma unroll
    for (int r = 0; r < 32; ++r) {
      float4 hv = *(const float4*)&hl[r * 128 + kk];
      acc[r] += hv.x * w0 + hv.y * w1 + hv.z * w2 + hv.w * w3;
    }
  }
  #pragma unroll
  for (int r = 0; r < 32; ++r)
    part[((size_t)(rb + r) * 8 + kq) * CE + t] = acc[r];
}

// model_loss = (sum(partials)+bm2 - emb)^2
__global__ void ml_kernel(const float* __restrict__ part, const float* __restrict__ bm2,
                          const float* __restrict__ emb, float* __restrict__ ML) {
  int idx = blockIdx.x * 256 + threadIdx.x;   // < 2048*256
  int b = idx >> 8, e = idx & 255;
  float outv = bm2[e];
  #pragma unroll
  for (int q = 0; q < 8; ++q) outv += part[((size_t)b * 8 + q) * CE + e];
  float d = outv - emb[idx];
  ML[idx] = d * d;
}

// ---------------------------------------------------------------------------
// plan2: 256 blocks = 64 independent chains x 4 j-quarter blocks, 512 thr.
// The 64 planning chains are vmapped-independent in the reference; the ONLY
// cross-block op is summing the 4 layer-2 quarter-partials at the next
// epilogue. Each quarter-block replicates the chain state (X, logits, I,
// push) in LDS and computes the decision redundantly (deterministic f32 ->
// bit-identical). Flags: per (n,q) private cache line, parity-double-buffered
// parts; writer of part(s) passed wait-flags(s-1), which were posted only
// after every peer read part(s-2) -> no overwrite race. Pop steps: zero
// cross-block traffic. No global barriers, no contended lines, no convoy.
// ---------------------------------------------------------------------------
__global__ __launch_bounds__(512) void plan2_kernel(
    const float* __restrict__ Wpm, const float* __restrict__ Wm2T,
    const float* __restrict__ bm1g, const int* __restrict__ P,
    const float* __restrict__ Wsg, const float* __restrict__ bsg,
    const float* __restrict__ Wcg, const float* __restrict__ bcg,
    const float* __restrict__ bm2, float* __restrict__ Xout,
    float* __restrict__ SLout, float* __restrict__ VALout,
    float* __restrict__ PAout, int* __restrict__ flg,
    float* __restrict__ part_db) {
  __shared__ float Xlds[CHP * CE];      // replicated plan buffer (8 KB)
  __shared__ float sxs[512];            // [relu(x); relu(-x)]
  __shared__ float sh[256];             // h quarter
  __shared__ float red[512];            // 2-way k-split partials (reused)
  __shared__ float sx[256];
  __shared__ float sred[256];
  __shared__ float svals[32];
  __shared__ float sxtra[2];
  __shared__ int   sint[4];
  __shared__ float logits_s[32];

  int bid = blockIdx.x, t = threadIdx.x;
  int n = bid >> 2, q = bid & 3;
  int jb = q * 256;
  int c2 = t >> 3, g = t & 7;
  int half = t >> 8, j = t & 255;

  // prologue: replicated chain state
  for (int idx = t; idx < CHP * CE; idx += 512)
    Xlds[idx] = Xout[(size_t)n * (CHP * CE) + idx];
  if (t < 32) logits_s[t] = 0.f;
  if (t < 4) sint[t] = 0;
  __syncthreads();

  for (int s = 0; s <= CS; ++s) {
    // read-only prefetch (L2-warm; hidden under the flag wait when pushing)
    float wsv = 0.f, bm2v = 0.f, bcv = 0.f, bsv = bsg[0];
    float wcv[32];
    if (t < 256) {
      wsv = Wsg[t]; bm2v = bm2[t];
      #pragma unroll
      for (int i = 0; i < 32; ++i) wcv[i] = Wcg[c2 * CE + g * 32 + i];
    }
    if (t < CA) bcv = bcg[t];

    // ---- epilogue of step s-1 ----
    if (s > 0) {
      if (sint[SI_PUSH]) {
        if (t < 4) {
          const int* fp = &flg[(n * 4 + t) * 16];
          while (gldi(fp) < s) __builtin_amdgcn_s_sleep(1);
        }
        __syncthreads();
        int Iup = sint[SI_IUP];
        if (t < 256) {
          int par = (s - 1) & 1;
          float outv = bm2v;
          #pragma unroll
          for (int qq = 0; qq < 4; ++qq)
            outv += gld(&part_db[(((size_t)par * CN + n) * 4 + qq) * CE + t]);
          Xlds[Iup * CE + t] = outv;
          if (q == 0) Xout[((size_t)(n * CHP) + Iup) * CE + t] = outv;
          sx[t] = outv;
        }
        if (t == 0) sint[SI_I] = Iup;
      } else {
        int I = sint[SI_I];
        int Inew = (I - 1 > 0) ? I - 1 : 0;
        if (t < 256) sx[t] = Xlds[Inew * CE + t];
        if (t == 0) sint[SI_I] = Inew;
      }
      if (s == CS) break;  // final epilogue only (uniform)
    } else {
      if (t < 256) sx[t] = Xlds[t];
      if (t == 0) sint[SI_I] = 0;
    }
    __syncthreads();
    int I = sint[SI_I];

    // ---- decision (replicated identically in all 4 q-blocks) ----
    if (t < 256) {
      float xv = sx[t];
      float xa = fmaxf(xv, 0.f);
      sxs[t] = xa;
      sxs[256 + t] = fmaxf(-xv, 0.f);
      sred[t] = xa * wsv;
    }
    __syncthreads();
    #pragma unroll
    for (int off = 128; off > 0; off >>= 1) {
      if (t < off) sred[t] += sred[t + off];
      __syncthreads();
    }
    if (t == 0) { sxtra[0] = sred[0] + bsv; sint[SI_FLAG] = 1; }
    if (t < 256) {
      float pv = 0.f;
      #pragma unroll 4
      for (int i = 0; i < 32; ++i)
        pv += fmaxf(sx[g * 32 + i], 0.f) * wcv[i];
      pv += __shfl_down(pv, 4, 8);
      pv += __shfl_down(pv, 2, 8);
      pv += __shfl_down(pv, 1, 8);
      if (g == 0) svals[c2] = pv + bcv;
    }
    __syncthreads();
    if (t < CA && logits_s[t] != 0.f) sint[SI_FLAG] = 0;
    __syncthreads();
    int a = P[s * CN + n];
    if (t < CA) {
      float v = svals[t];
      float slv = sint[SI_FLAG] ? sxtra[0] * v : logits_s[t];
      if (q == 0) SLout[(size_t)(s * CN + n) * CA + t] = slv;
      logits_s[t] = slv - (t == a ? 1e8f : 0.f);
      if (t == a) {
        if (q == 0) { VALout[s * CN + n] = slv; PAout[n * CHP + I] = (float)a; }
        sint[SI_PUSH] = (v > 0.f) ? 1 : 0;
        sint[SI_IUP] = (I + 1 < CHP - 1) ? I + 1 : CHP - 1;
      }
    }
    __syncthreads();

    // ---- model eval (push only): this block's j-quarter, W streamed ----
    if (sint[SI_PUSH]) {
      // l1: red[half][j] = sum_{k in half's 256} sxs[half*256+k]*Wpm[o][..][jb+j]
      const float* wb = Wpm + ((size_t)a * 512 + (size_t)half * 256) * CHID + jb + j;
      const float* xk = sxs + half * 256;
      float acc = 0.f;
      #pragma unroll 8
      for (int k = 0; k < 256; ++k)
        acc = fmaf(xk[k], wb[(size_t)k * CHID], acc);
      red[half * 256 + j] = acc;
      __syncthreads();
      if (t < 256) sh[t] = fmaxf(red[t] + red[256 + t] + bm1g[jb + t], 0.f);
      __syncthreads();
      // l2: part_q[e] = sum_{kl<256} sh[kl] * Wm2T[(jb+kl)*CE+e], 2x128 split
      {
        const float* w2 = Wm2T + (size_t)(jb + half * 128) * CE + j;
        float a2 = 0.f;
        #pragma unroll 8
        for (int kl = 0; kl < 128; ++kl)
          a2 = fmaf(sh[half * 128 + kl], w2[(size_t)kl * CE], a2);
        red[half * 256 + j] = a2;
      }
      __syncthreads();
      if (t < 256) {
        int par = s & 1;
        gst(&part_db[(((size_t)par * CN + n) * 4 + q) * CE + t],
            red[t] + red[256 + t]);
      }
      __syncthreads();            // drains all stores (vmcnt before s_barrier)
      if (t == 0) {
        waitst();
        gsti(&flg[(n * 4 + q) * 16], s + 1);
      }
    }
    __syncthreads();
  }
}

// ---------------------------------------------------------------------------
// embed_loss
// ---------------------------------------------------------------------------
__global__ void el_kernel(const float* __restrict__ emb, const float* __restrict__ Xout,
                          const float* __restrict__ Ws, const float* __restrict__ bsp,
                          float* __restrict__ EL) {
  int tn = blockIdx.x;
  int n = tn & 63;
  int t = threadIdx.x, h = t >> 5, l = t & 31;
  const float* er = emb + (size_t)tn * CE;
  const float* xr = Xout + ((size_t)(n * CHP) + h) * CE;
  float pd = 0.f, px = 0.f, pe = 0.f, ps = 0.f;
  #pragma unroll
  for (int i = 0; i < 8; ++i) {
    int e = l * 8 + i;
    float ev = er[e], xv2 = xr[e];
    pd += ev * xv2; px += xv2 * xv2; pe += ev * ev; ps += fmaxf(ev, 0.f) * Ws[e];
  }
  #pragma unroll
  for (int off = 16; off > 0; off >>= 1) {
    pd += __shfl_down(pd, off, 32);
    px += __shfl_down(px, off, 32);
    pe += __shfl_down(pe, off, 32);
    ps += __shfl_down(ps, off, 32);
  }
  __shared__ float sdot[8], snx[8];
  __shared__ float sne, ssh;
  if (l == 0) {
    sdot[h] = pd;
    snx[h] = sqrtf(px);
    if (h == 0) { sne = sqrtf(pe); ssh = ps + bsp[0]; }
  }
  __syncthreads();
  if (t == 0) {
    const float eps = 1e-8f;
    float y[8];
    float m = -1e30f;
    #pragma unroll
    for (int hh = 0; hh < 8; ++hh) {
      float cs = sdot[hh] / ((sne + eps) * (snx[hh] + eps));
      y[hh] = ssh * cs;
      m = fmaxf(m, y[hh]);
    }
    float sum = 0.f;
    #pragma unroll
    for (int hh = 0; hh < 8; ++hh) sum += expf(y[hh] - m);
    float lse = logf(sum);
    float el = 0.f;
    #pragma unroll
    for (int hh = 0; hh < 8; ++hh) {
      float lp = y[hh] - m - lse;
      el += expf(lp) * lp;
    }
    EL[tn] = el;
  }
}

// ---------------------------------------------------------------------------
extern "C" void kernel_launch(void* const* d_in, const int* in_sizes, int n_in,
                              void* d_out, int out_size, void* d_ws, size_t ws_size,
                              hipStream_t stream) {
  (void)in_sizes; (void)n_in; (void)out_size; (void)ws_size;
  const int*   obs    = (const int*)d_in[0];
  const int*   P      = (const int*)d_in[1];
  const float* embed1 = (const float*)d_in[2];
  const float* Wih    = (const float*)d_in[3];
  // d_in[4] = Whh: provably unused (h0 = 0 and only Hs[0] is consumed)
  const float* bih    = (const float*)d_in[5];
  const float* bhh    = (const float*)d_in[6];
  const float* We2    = (const float*)d_in[7];
  const float* be2    = (const float*)d_in[8];
  const float* Ws     = (const float*)d_in[9];
  const float* bs     = (const float*)d_in[10];
  const float* Wc     = (const float*)d_in[11];
  const float* bc     = (const float*)d_in[12];
  const float* Wm1    = (const float*)d_in[13];
  const float* bm1    = (const float*)d_in[14];
  const float* Wm2    = (const float*)d_in[15];
  const float* bm2    = (const float*)d_in[16];
  const float* eo     = (const float*)d_in[17];
  float* out = (float*)d_out;
  char*  ws  = (char*)d_ws;

  float* emb    = (float*)(ws + B_EMB);
  float* h1     = (float*)(ws + B_H1);
  float* part_db= (float*)(ws + B_PART);
  int*   flg    = (int*)(ws + B_FLG);
  int*   cnttl  = (int*)(ws + B_CNTTL);
  int*   listtl = (int*)(ws + B_LISTTL);
  float* we2t   = (float*)(ws + B_WE2T);
  float* wm1t   = (float*)(ws + B_WM1T);
  float* xstl   = (float*)(ws + B_XSTL);
  float* hbig   = (float*)(ws + B_HBIG);
  float* parttl = (float*)(ws + B_PARTTL);
  float* wm2t   = (float*)(ws + B_WM2T);
  float* wpm    = (float*)(ws + B_WPM);

  dim3 thr(256);
  init_kernel<<<dim3(514), thr, 0, stream>>>(out, flg, cnttl);
  emb_kernel<<<dim3(256), thr, 0, stream>>>(obs, embed1, emb);
  h1_kernel<<<dim3(256), thr, 0, stream>>>(emb, Wih, bih, bhh, h1);
  trans_kernel<<<dim3(16, 4), thr, 0, stream>>>(We2, we2t, CE, CHID);        // We2T
  x0_kernel<<<dim3(4, 64), thr, 0, stream>>>(h1, we2t, be2, out + O_X);
  trans_kernel<<<dim3(128, 16), thr, 0, stream>>>(Wm1, wm1t, CHID, CA * CE); // Wm1T
  wpm_kernel<<<dim3(256, 4), thr, 0, stream>>>(wm1t, eo, wpm);
  trans_kernel<<<dim3(16, 4), thr, 0, stream>>>(Wm2, wm2t, CE, CHID);        // Wm2T
  tllists_kernel<<<dim3(8), thr, 0, stream>>>(P, cnttl, listtl);
  xstl_kernel<<<dim3(4096), thr, 0, stream>>>(emb, xstl);
  // time-loop model (factorized, f32)
  l1_kernel<<<dim3(32, 8, 8), thr, 0, stream>>>(wpm, xstl, bm1, cnttl, listtl, 256, hbig);
  l2big_kernel<<<dim3(8, 64), thr, 0, stream>>>(hbig, wm2t, parttl);
  ml_kernel<<<dim3(2048), thr, 0, stream>>>(parttl, bm2, emb, out + O_ML);
  // planning loop: 64 independent chains x 4 quarter-blocks, flag handoffs only
  plan2_kernel<<<dim3(256), dim3(512), 0, stream>>>(
      wpm, wm2t, bm1, P, Ws, bs, Wc, bc, bm2,
      out + O_X, out + O_SL, out + O_VAL, out + O_PA, flg, part_db);
  el_kernel<<<dim3(2048), thr, 0, stream>>>(emb, out + O_X, Ws, bs, out + O_EL);
}

// Round 11
// 650.856 us; speedup vs baseline: 1.4116x; 1.0682x over previous
//
#include <hip/hip_runtime.h>

// ---------------------------------------------------------------------------
// Problem constants
// ---------------------------------------------------------------------------
constexpr int CT = 32;      // T
constexpr int CN = 64;      // N
constexpr int CE = 256;     // E = DOBS*V
constexpr int CHID = 1024;
constexpr int CA = 32;      // num options
constexpr int CS = 32;      // planning steps
constexpr int CHP = 8;      // planning horizon
constexpr int TN = CT * CN; // 2048

// d_out float offsets (return order: search_logits, planned_actions, X, value,
// model_loss, embed_loss)
constexpr size_t O_SL  = 0;        // 32*64*32 = 65536
constexpr size_t O_PA  = 65536;    // 64*8     = 512
constexpr size_t O_X   = 66048;    // 64*8*256 = 131072
constexpr size_t O_VAL = 197120;   // 32*64    = 2048
constexpr size_t O_ML  = 199168;   // 32*64*256= 524288
constexpr size_t O_EL  = 723456;   // 32*64    = 2048

// ws byte offsets (~100 MB total)
constexpr size_t B_EMB    = 0;                           // 2 MB   [2048][256] f32
constexpr size_t B_H1     = 2u * 1024 * 1024;            // 256 KB [64][1024]
// control block at 3.5 MB (safe: nothing else lives in 3.5..4 MB)
constexpr size_t B_FLG    = 3584u * 1024;                // 64*8*16 ints = 32 KB
constexpr size_t B_CNTTL  = B_FLG + 64 * 1024;           // 32 ints
constexpr size_t B_LISTTL = B_CNTTL + 4 * 1024;          // 32 KB [32][256]
// 32MB+ multi-phase region: We2T (early) -> Wm1T (mid) -> xstl/hbig/parttl/Wm2T
constexpr size_t B_R32    = 4u * 1024 * 1024;
constexpr size_t B_WE2T   = B_R32;                       // 1 MB  (dead after x0)
constexpr size_t B_WM1T   = B_R32;                       // 32 MB (dead after wpm)
constexpr size_t B_XSTL   = B_R32;                       // 4 MB  [2048][512]
constexpr size_t B_HBIG   = B_R32 + 4u * 1024 * 1024;    // 8 MB  [2048][1024]
constexpr size_t B_PARTTL = B_R32 + 12u * 1024 * 1024;   // 16 MB [2048][8][256]
// plan part buffer REUSES the parttl region (dead after ml_kernel, which is
// stream-ordered before plan2). ROUND-10 BUG: part_db at 2.5MB overlapped
// B_FLG at 3.5MB -> part stores clobbered spin flags -> deadlock/timeout.
constexpr size_t B_PART2  = B_PARTTL;                    // 1.5 MB [3 par][64][8][256]
constexpr size_t B_WM2T   = B_R32 + 28u * 1024 * 1024;   // 1 MB  [1024][256]
constexpr size_t B_WPM    = B_R32 + 32u * 1024 * 1024;   // 64 MB [32][512][1024]

// LDS scalar-state indices
constexpr int SI_FLAG = 0, SI_I = 1, SI_PUSH = 2, SI_IUP = 3;

__device__ __forceinline__ void fma4(float4& a, float s, const float4& w) {
  a.x = fmaf(s, w.x, a.x); a.y = fmaf(s, w.y, a.y);
  a.z = fmaf(s, w.z, a.z); a.w = fmaf(s, w.w, a.w);
}

// LLC-coherent relaxed accessors (cross-block data; no fences needed: producer
// ordering via __syncthreads' vmcnt drain + explicit waitst before flag post)
__device__ __forceinline__ float gld(const float* p) {
  return __hip_atomic_load(p, __ATOMIC_RELAXED, __HIP_MEMORY_SCOPE_AGENT);
}
__device__ __forceinline__ void gst(float* p, float v) {
  __hip_atomic_store(p, v, __ATOMIC_RELAXED, __HIP_MEMORY_SCOPE_AGENT);
}
__device__ __forceinline__ int gldi(const int* p) {
  return __hip_atomic_load(p, __ATOMIC_RELAXED, __HIP_MEMORY_SCOPE_AGENT);
}
__device__ __forceinline__ void gsti(int* p, int v) {
  __hip_atomic_store(p, v, __ATOMIC_RELAXED, __HIP_MEMORY_SCOPE_AGENT);
}
__device__ __forceinline__ void waitst() {
  asm volatile("s_waitcnt vmcnt(0)" ::: "memory");
}

// ---------------------------------------------------------------------------
// init: zero PA+X span of d_out, per-chain flags, time-loop counters
// ---------------------------------------------------------------------------
__global__ void init_kernel(float* __restrict__ out, int* __restrict__ flg,
                            int* __restrict__ cnt_tl) {
  int idx = blockIdx.x * 256 + threadIdx.x;
  if (idx < 131584) out[O_PA + idx] = 0.f;  // PA (512) + X (131072) contiguous
  if (idx < CN * 8 * 16) flg[idx] = 0;
  if (idx < CA) cnt_tl[idx] = 0;
}

// ---------------------------------------------------------------------------
// emb[t][n][e] = embed1[obs[t][n][e>>4]][e&15]
// ---------------------------------------------------------------------------
__global__ void emb_kernel(const int* __restrict__ obs, const float* __restrict__ embed1,
                           float* __restrict__ emb) {
  int idx = blockIdx.x * 256 + threadIdx.x;
  int b = idx >> 5, k8 = idx & 31;
  int e0 = k8 * 8;
  int d = e0 >> 4;
  int o = obs[b * 16 + d];
  const float* src = embed1 + o * 16 + (e0 & 15);
  float4 v0 = *(const float4*)src;
  float4 v1 = *(const float4*)(src + 4);
  float* dst = emb + (size_t)b * CE + e0;
  *(float4*)dst = v0;
  *(float4*)(dst + 4) = v1;
}

// ---------------------------------------------------------------------------
// One GRU step with h0 = 0 (only Hs[0] used downstream; Whh provably unused)
// ---------------------------------------------------------------------------
__global__ void h1_kernel(const float* __restrict__ emb, const float* __restrict__ Wih,
                          const float* __restrict__ bih, const float* __restrict__ bhh,
                          float* __restrict__ h1) {
  int t = threadIdx.x, bid = blockIdx.x;   // 256 blocks of (64n x 4j)
  int n = t & 63, j = bid * 4 + (t >> 6);
  const float* x = emb + (size_t)n * CE;   // emb[0] rows
  const float* wr = Wih + (size_t)j * CE;
  const float* wz = Wih + (size_t)(CHID + j) * CE;
  const float* wn = Wih + (size_t)(2 * CHID + j) * CE;
  float ar = 0.f, az = 0.f, an = 0.f;
  #pragma unroll 4
  for (int e = 0; e < CE; ++e) {
    float xe = x[e];
    ar += xe * wr[e]; az += xe * wz[e]; an += xe * wn[e];
  }
  ar += bih[j] + bhh[j];
  az += bih[CHID + j] + bhh[CHID + j];
  float r = 1.f / (1.f + expf(-ar));
  float z = 1.f / (1.f + expf(-az));
  float nn = tanhf(an + bih[2 * CHID + j] + r * bhh[2 * CHID + j]);
  h1[(size_t)n * CHID + j] = (1.f - z) * nn;
}

// ---------------------------------------------------------------------------
// Generic 64x64 tiled transpose: in[R][C] -> out[C][R]
// ---------------------------------------------------------------------------
__global__ void trans_kernel(const float* __restrict__ in, float* __restrict__ out,
                             int R, int C) {
  __shared__ float tile[64][65];
  int tj = threadIdx.x & 63, tg = threadIdx.x >> 6;
  int cb = blockIdx.x * 64, rb = blockIdx.y * 64;
  #pragma unroll
  for (int i = 0; i < 16; ++i) {
    int r = tg * 16 + i;
    tile[r][tj] = in[(size_t)(rb + r) * C + cb + tj];
  }
  __syncthreads();
  #pragma unroll
  for (int i = 0; i < 16; ++i) {
    int c2 = tg * 16 + i;
    out[(size_t)(cb + c2) * R + rb + tj] = tile[tj][c2];
  }
}

// ---------------------------------------------------------------------------
// X[:,0] = h1 @ We2^T + be2   (We2T layout [k][e])
// ---------------------------------------------------------------------------
__global__ void x0_kernel(const float* __restrict__ h1, const float* __restrict__ We2T,
                          const float* __restrict__ be2, float* __restrict__ Xout) {
  int et = blockIdx.x, n = blockIdx.y, t = threadIdx.x;
  int el = t & 63, kq = t >> 6;
  __shared__ float hr[1024];
  __shared__ float sred2[4][64];
  for (int idx = t; idx < 1024; idx += 256) hr[idx] = h1[(size_t)n * CHID + idx];
  __syncthreads();
  int e = et * 64 + el;
  float acc = 0.f;
  for (int k = kq * 256; k < kq * 256 + 256; ++k) acc += hr[k] * We2T[(size_t)k * CE + e];
  sred2[kq][el] = acc;
  __syncthreads();
  if (t < 64) {
    float s2 = sred2[0][t] + sred2[1][t] + sred2[2][t] + sred2[3][t] + be2[et * 64 + t];
    Xout[(size_t)(n * CHP) * CE + et * 64 + t] = s2;
  }
}

// ---------------------------------------------------------------------------
// Factorized model weights:
// Wpm[o][e][j]     = sum_a relu( embed_opt[o][a]) * Wm1[j][a*256+e]
// Wpm[o][256+e][j] = sum_a relu(-embed_opt[o][a]) * Wm1[j][a*256+e]
// ---------------------------------------------------------------------------
__global__ void wpm_kernel(const float* __restrict__ Wm1T, const float* __restrict__ eo,
                           float* __restrict__ Wpm) {
  int e = blockIdx.x, jt = blockIdx.y, t = threadIdx.x;
  int j = jt * 256 + t;
  __shared__ float rp[CA * CA], rm[CA * CA];
  for (int idx = t; idx < CA * CA; idx += 256) {
    float v = eo[idx];
    rp[idx] = fmaxf(v, 0.f);
    rm[idx] = fmaxf(-v, 0.f);
  }
  __syncthreads();
  float w[32];
  #pragma unroll
  for (int a = 0; a < 32; ++a) w[a] = Wm1T[(size_t)(a * 256 + e) * CHID + j];
  for (int o = 0; o < 32; ++o) {
    float sp = 0.f, sm = 0.f;
    #pragma unroll
    for (int a = 0; a < 32; ++a) {
      float wa = w[a];
      sp += rp[o * 32 + a] * wa;
      sm += rm[o * 32 + a] * wa;
    }
    Wpm[((size_t)o * 512 + e) * CHID + j] = sp;
    Wpm[((size_t)o * 512 + 256 + e) * CHID + j] = sm;
  }
}

// ---------------------------------------------------------------------------
// Group time-loop rows by option (list order nondeterministic; results aren't)
// ---------------------------------------------------------------------------
__global__ void tllists_kernel(const int* __restrict__ P, int* __restrict__ cnt_tl,
                               int* __restrict__ list_tl) {
  int b = blockIdx.x * 256 + threadIdx.x;
  if (b >= TN) return;
  int a = P[b];
  int slot = atomicAdd(&cnt_tl[a], 1);
  list_tl[a * 256 + slot] = b;
}

// xs_tl[b][k] = relu(+/- prev[b][k&255]),  prev = emb shifted by one t (wrap)
__global__ void xstl_kernel(const float* __restrict__ emb, float* __restrict__ xs) {
  int idx = blockIdx.x * 256 + threadIdx.x;   // < 2048*512
  int b = idx >> 9, k = idx & 511;
  int e = k & 255;
  int bp = (b < CN) ? (b + (CT - 1) * CN) : (b - CN);
  float v = emb[(size_t)bp * CE + e];
  xs[idx] = (k < 256) ? fmaxf(v, 0.f) : fmaxf(-v, 0.f);
}

// ---------------------------------------------------------------------------
// Time-loop factorized model layer 1:
// h[row][j] = relu( sum_{k<512} xs[row][k] * Wpm[o][k][j] + bm1[j] )
// grid (32 o, 8 j-tiles of 128, z row-group start)
// ---------------------------------------------------------------------------
__global__ __launch_bounds__(256) void l1_kernel(
    const float* __restrict__ Wpm, const float* __restrict__ xs,
    const float* __restrict__ bm1, const int* __restrict__ cnt,
    const int* __restrict__ list, int listStride, float* __restrict__ hout) {
  int o = blockIdx.x, jt = blockIdx.y;
  int c = cnt[o];
  if (c <= 0) return;
  __shared__ __align__(16) float sbuf[8192];
  __shared__ int srows[8];
  int t = threadIdx.x;
  int jl = t & 31, kq = t >> 5;
  int jb = jt * 128;
  const float* wb = Wpm + (size_t)o * (512 * CHID) + jb + jl * 4;
  for (int g = blockIdx.z; g * 8 < c; g += gridDim.z) {
    int base = g * 8;
    int nr = min(8, c - base);
    if (t < 8) srows[t] = (t < nr) ? list[o * listStride + base + t] : -1;
    __syncthreads();
    for (int idx = t; idx < 4096; idx += 256) {
      int row = srows[idx >> 9];
      sbuf[idx] = (row >= 0) ? xs[(size_t)row * 512 + (idx & 511)] : 0.f;
    }
    __syncthreads();
    float4 acc[8];
    #pragma unroll
    for (int r = 0; r < 8; ++r) acc[r] = make_float4(0.f, 0.f, 0.f, 0.f);
    int kbase = kq * 64;
    for (int k4 = 0; k4 < 64; k4 += 4) {
      int k = kbase + k4;
      float4 w0 = *(const float4*)(wb + (size_t)(k + 0) * CHID);
      float4 w1 = *(const float4*)(wb + (size_t)(k + 1) * CHID);
      float4 w2 = *(const float4*)(wb + (size_t)(k + 2) * CHID);
      float4 w3 = *(const float4*)(wb + (size_t)(k + 3) * CHID);
      #pragma unroll
      for (int r = 0; r < 8; ++r) {
        float4 xv = *(const float4*)&sbuf[r * 512 + k];
        fma4(acc[r], xv.x, w0); fma4(acc[r], xv.y, w1);
        fma4(acc[r], xv.z, w2); fma4(acc[r], xv.w, w3);
      }
    }
    __syncthreads();
    #pragma unroll
    for (int r = 0; r < 8; ++r)
      *(float4*)&sbuf[(kq * 8 + r) * 128 + jl * 4] = acc[r];
    __syncthreads();
    for (int idx = t; idx < 1024; idx += 256) {
      int r = idx >> 7, jc = idx & 127;
      float s = 0.f;
      #pragma unroll
      for (int q = 0; q < 8; ++q) s += sbuf[(q * 8 + r) * 128 + jc];
      int row = srows[r];
      if (row >= 0)
        hout[(size_t)row * CHID + jb + jc] = fmaxf(s + bm1[jb + jc], 0.f);
    }
    __syncthreads();
  }
}

// ---------------------------------------------------------------------------
// Time-loop layer 2 partials: part[b][kq][e], 8 k-slices of 128
// grid (8 kq, 64 row-groups of 32), 256 thr (= e)
// ---------------------------------------------------------------------------
__global__ __launch_bounds__(256) void l2big_kernel(const float* __restrict__ h,
    const float* __restrict__ Wm2T, float* __restrict__ part) {
  int kq = blockIdx.x, rg = blockIdx.y, t = threadIdx.x;
  int rb = rg * 32, kb = kq * 128;
  __shared__ __align__(16) float hl[4096];
  for (int idx = t; idx < 4096; idx += 256)
    hl[idx] = h[(size_t)(rb + (idx >> 7)) * CHID + kb + (idx & 127)];
  __syncthreads();
  float acc[32];
  #pragma unroll
  for (int r = 0; r < 32; ++r) acc[r] = 0.f;
  for (int kk = 0; kk < 128; kk += 4) {
    float w0 = Wm2T[(size_t)(kb + kk + 0) * CE + t];
    float w1 = Wm2T[(size_t)(kb + kk + 1) * CE + t];
    float w2 = Wm2T[(size_t)(kb + kk + 2) * CE + t];
    float w3 = Wm2T[(size_t)(kb + kk + 3) * CE + t];
    #pragma unroll
    for (int r = 0; r < 32; ++r) {
      float4 hv = *(const float4*)&hl[r * 128 + kk];
      acc[r] += hv.x * w0 + hv.y * w1 + hv.z * w2 + hv.w * w3;
    }
  }
  #pragma unroll
  for (int r = 0; r < 32; ++r)
    part[((size_t)(rb + r) * 8 + kq) * CE + t] = acc[r];
}

// model_loss = (sum(partials)+bm2 - emb)^2
__global__ void ml_kernel(const float* __restrict__ part, const float* __restrict__ bm2,
                          const float* __restrict__ emb, float* __restrict__ ML) {
  int idx = blockIdx.x * 256 + threadIdx.x;   // < 2048*256
  int b = idx >> 8, e = idx & 255;
  float outv = bm2[e];
  #pragma unroll
  for (int q = 0; q < 8; ++q) outv += part[((size_t)b * 8 + q) * CE + e];
  float d = outv - emb[idx];
  ML[idx] = d * d;
}

// ---------------------------------------------------------------------------
// plan2: 512 blocks = 64 independent chains x 8 j-eighth blocks, 512 thr.
// Chains are vmapped-independent; the only cross-block op is summing the 8
// layer-2 eighth-partials at the next epilogue (per-(n,q) private flag lines,
// parts triple-buffered by s%3, living in the dead parttl region). Decision
// replicated bit-identically in all 8 blocks. l1 weight stream via float4
// loads (1 KB/instr/wave, 4x in-flight bytes) + 8-way split (2 blocks/CU).
// ---------------------------------------------------------------------------
__global__ __launch_bounds__(512) void plan2_kernel(
    const float* __restrict__ Wpm, const float* __restrict__ Wm2T,
    const float* __restrict__ bm1g, const int* __restrict__ P,
    const float* __restrict__ Wsg, const float* __restrict__ bsg,
    const float* __restrict__ Wcg, const float* __restrict__ bcg,
    const float* __restrict__ bm2, float* __restrict__ Xout,
    float* __restrict__ SLout, float* __restrict__ VALout,
    float* __restrict__ PAout, int* __restrict__ flg,
    float* __restrict__ part_db) {
  __shared__ float Xlds[CHP * CE];      // replicated plan buffer (8 KB)
  __shared__ float sxs[512];            // [relu(x); relu(-x)]
  __shared__ float sh[128];             // h eighth
  __shared__ __align__(16) float red[2048];  // 16-way k-split partials / l2 halves
  __shared__ float sx[256];
  __shared__ float sred[256];
  __shared__ float svals[32];
  __shared__ float sxtra[2];
  __shared__ int   sint[4];
  __shared__ float logits_s[32];

  int bid = blockIdx.x, t = threadIdx.x;
  int n = bid >> 3, q = bid & 7;
  int jb = q * 128;
  int c2 = t >> 3, g = t & 7;
  int jq = t & 31, kg = t >> 5;         // l1: jq = float4 j-lane, kg = k-group
  int e2 = t & 255, hf = t >> 8;        // l2: e lane, kl half

  // prologue: replicated chain state
  for (int idx = t; idx < CHP * CE; idx += 512)
    Xlds[idx] = Xout[(size_t)n * (CHP * CE) + idx];
  if (t < 32) logits_s[t] = 0.f;
  if (t < 4) sint[t] = 0;
  __syncthreads();

  for (int s = 0; s <= CS; ++s) {
    // read-only prefetch (L2-warm; hidden under the flag wait when pushing)
    float wsv = 0.f, bm2v = 0.f, bcv = 0.f, bsv = bsg[0];
    float wcv[32];
    if (t < 256) {
      wsv = Wsg[t]; bm2v = bm2[t];
      #pragma unroll
      for (int i = 0; i < 32; ++i) wcv[i] = Wcg[c2 * CE + g * 32 + i];
    }
    if (t < CA) bcv = bcg[t];

    // ---- epilogue of step s-1 ----
    if (s > 0) {
      if (sint[SI_PUSH]) {
        if (t < 8) {
          const int* fp = &flg[(n * 8 + t) * 16];
          while (gldi(fp) < s) __builtin_amdgcn_s_sleep(1);
        }
        __syncthreads();
        int Iup = sint[SI_IUP];
        if (t < 256) {
          int par = (s - 1) % 3;
          float outv = bm2v;
          #pragma unroll
          for (int qq = 0; qq < 8; ++qq)
            outv += gld(&part_db[(((size_t)par * CN + n) * 8 + qq) * CE + t]);
          Xlds[Iup * CE + t] = outv;
          if (q == 0) Xout[((size_t)(n * CHP) + Iup) * CE + t] = outv;
          sx[t] = outv;
        }
        if (t == 0) sint[SI_I] = Iup;
      } else {
        int I = sint[SI_I];
        int Inew = (I - 1 > 0) ? I - 1 : 0;
        if (t < 256) sx[t] = Xlds[Inew * CE + t];
        if (t == 0) sint[SI_I] = Inew;
      }
      if (s == CS) break;  // final epilogue only (uniform)
    } else {
      if (t < 256) sx[t] = Xlds[t];
      if (t == 0) sint[SI_I] = 0;
    }
    __syncthreads();
    int I = sint[SI_I];

    // ---- decision (replicated identically in all 8 q-blocks) ----
    if (t < 256) {
      float xv = sx[t];
      float xa = fmaxf(xv, 0.f);
      sxs[t] = xa;
      sxs[256 + t] = fmaxf(-xv, 0.f);
      sred[t] = xa * wsv;
    }
    __syncthreads();
    #pragma unroll
    for (int off = 128; off > 0; off >>= 1) {
      if (t < off) sred[t] += sred[t + off];
      __syncthreads();
    }
    if (t == 0) { sxtra[0] = sred[0] + bsv; sint[SI_FLAG] = 1; }
    if (t < 256) {
      float pv = 0.f;
      #pragma unroll 4
      for (int i = 0; i < 32; ++i)
        pv += fmaxf(sx[g * 32 + i], 0.f) * wcv[i];
      pv += __shfl_down(pv, 4, 8);
      pv += __shfl_down(pv, 2, 8);
      pv += __shfl_down(pv, 1, 8);
      if (g == 0) svals[c2] = pv + bcv;
    }
    __syncthreads();
    if (t < CA && logits_s[t] != 0.f) sint[SI_FLAG] = 0;
    __syncthreads();
    int a = P[s * CN + n];
    if (t < CA) {
      float v = svals[t];
      float slv = sint[SI_FLAG] ? sxtra[0] * v : logits_s[t];
      if (q == 0) SLout[(size_t)(s * CN + n) * CA + t] = slv;
      logits_s[t] = slv - (t == a ? 1e8f : 0.f);
      if (t == a) {
        if (q == 0) { VALout[s * CN + n] = slv; PAout[n * CHP + I] = (float)a; }
        sint[SI_PUSH] = (v > 0.f) ? 1 : 0;
        sint[SI_IUP] = (I + 1 < CHP - 1) ? I + 1 : CHP - 1;
      }
    }
    __syncthreads();

    // ---- model eval (push only): this block's j-eighth, W streamed float4 ----
    if (sint[SI_PUSH]) {
      // l1: thread (kg, jq) does float4 over j = jb+jq*4, k in [kg*32, kg*32+32)
      const float* wb = Wpm + ((size_t)a * 512 + (size_t)kg * 32) * CHID + jb + jq * 4;
      const float* xk = sxs + kg * 32;
      float4 acc; acc.x = acc.y = acc.z = acc.w = 0.f;
      #pragma unroll
      for (int kk = 0; kk < 32; ++kk) {
        float4 wv = *(const float4*)(wb + (size_t)kk * CHID);
        fma4(acc, xk[kk], wv);
      }
      *(float4*)&red[kg * 128 + jq * 4] = acc;
      __syncthreads();
      if (t < 128) {
        float s1 = 0.f;
        #pragma unroll
        for (int gg = 0; gg < 16; ++gg) s1 += red[gg * 128 + t];
        sh[t] = fmaxf(s1 + bm1g[jb + t], 0.f);
      }
      __syncthreads();
      // l2: part_q[e] = sum_{kl<128} sh[kl] * Wm2T[(jb+kl)*CE+e], 2x64 split
      {
        const float* w2 = Wm2T + (size_t)(jb + hf * 64) * CE + e2;
        float a2 = 0.f;
        #pragma unroll 8
        for (int kl = 0; kl < 64; ++kl)
          a2 = fmaf(sh[hf * 64 + kl], w2[(size_t)kl * CE], a2);
        red[hf * 256 + e2] = a2;
      }
      __syncthreads();
      if (t < 256) {
        int par = s % 3;
        gst(&part_db[(((size_t)par * CN + n) * 8 + q) * CE + t],
            red[t] + red[256 + t]);
      }
      __syncthreads();            // drains all stores (vmcnt before s_barrier)
      if (t == 0) {
        waitst();
        gsti(&flg[(n * 8 + q) * 16], s + 1);
      }
    }
    __syncthreads();
  }
}

// ---------------------------------------------------------------------------
// embed_loss
// ---------------------------------------------------------------------------
__global__ void el_kernel(const float* __restrict__ emb, const float* __restrict__ Xout,
                          const float* __restrict__ Ws, const float* __restrict__ bsp,
                          float* __restrict__ EL) {
  int tn = blockIdx.x;
  int n = tn & 63;
  int t = threadIdx.x, h = t >> 5, l = t & 31;
  const float* er = emb + (size_t)tn * CE;
  const float* xr = Xout + ((size_t)(n * CHP) + h) * CE;
  float pd = 0.f, px = 0.f, pe = 0.f, ps = 0.f;
  #pragma unroll
  for (int i = 0; i < 8; ++i) {
    int e = l * 8 + i;
    float ev = er[e], xv2 = xr[e];
    pd += ev * xv2; px += xv2 * xv2; pe += ev * ev; ps += fmaxf(ev, 0.f) * Ws[e];
  }
  #pragma unroll
  for (int off = 16; off > 0; off >>= 1) {
    pd += __shfl_down(pd, off, 32);
    px += __shfl_down(px, off, 32);
    pe += __shfl_down(pe, off, 32);
    ps += __shfl_down(ps, off, 32);
  }
  __shared__ float sdot[8], snx[8];
  __shared__ float sne, ssh;
  if (l == 0) {
    sdot[h] = pd;
    snx[h] = sqrtf(px);
    if (h == 0) { sne = sqrtf(pe); ssh = ps + bsp[0]; }
  }
  __syncthreads();
  if (t == 0) {
    const float eps = 1e-8f;
    float y[8];
    float m = -1e30f;
    #pragma unroll
    for (int hh = 0; hh < 8; ++hh) {
      float cs = sdot[hh] / ((sne + eps) * (snx[hh] + eps));
      y[hh] = ssh * cs;
      m = fmaxf(m, y[hh]);
    }
    float sum = 0.f;
    #pragma unroll
    for (int hh = 0; hh < 8; ++hh) sum += expf(y[hh] - m);
    float lse = logf(sum);
    float el = 0.f;
    #pragma unroll
    for (int hh = 0; hh < 8; ++hh) {
      float lp = y[hh] - m - lse;
      el += expf(lp) * lp;
    }
    EL[tn] = el;
  }
}

// ---------------------------------------------------------------------------
extern "C" void kernel_launch(void* const* d_in, const int* in_sizes, int n_in,
                              void* d_out, int out_size, void* d_ws, size_t ws_size,
                              hipStream_t stream) {
  (void)in_sizes; (void)n_in; (void)out_size; (void)ws_size;
  const int*   obs    = (const int*)d_in[0];
  const int*   P      = (const int*)d_in[1];
  const float* embed1 = (const float*)d_in[2];
  const float* Wih    = (const float*)d_in[3];
  // d_in[4] = Whh: provably unused (h0 = 0 and only Hs[0] is consumed)
  const float* bih    = (const float*)d_in[5];
  const float* bhh    = (const float*)d_in[6];
  const float* We2    = (const float*)d_in[7];
  const float* be2    = (const float*)d_in[8];
  const float* Ws     = (const float*)d_in[9];
  const float* bs     = (const float*)d_in[10];
  const float* Wc     = (const float*)d_in[11];
  const float* bc     = (const float*)d_in[12];
  const float* Wm1    = (const float*)d_in[13];
  const float* bm1    = (const float*)d_in[14];
  const float* Wm2    = (const float*)d_in[15];
  const float* bm2    = (const float*)d_in[16];
  const float* eo     = (const float*)d_in[17];
  float* out = (float*)d_out;
  char*  ws  = (char*)d_ws;

  float* emb    = (float*)(ws + B_EMB);
  float* h1     = (float*)(ws + B_H1);
  float* part_db= (float*)(ws + B_PART2);
  int*   flg    = (int*)(ws + B_FLG);
  int*   cnttl  = (int*)(ws + B_CNTTL);
  int*   listtl = (int*)(ws + B_LISTTL);
  float* we2t   = (float*)(ws + B_WE2T);
  float* wm1t   = (float*)(ws + B_WM1T);
  float* xstl   = (float*)(ws + B_XSTL);
  float* hbig   = (float*)(ws + B_HBIG);
  float* parttl = (float*)(ws + B_PARTTL);
  float* wm2t   = (float*)(ws + B_WM2T);
  float* wpm    = (float*)(ws + B_WPM);

  dim3 thr(256);
  init_kernel<<<dim3(514), thr, 0, stream>>>(out, flg, cnttl);
  emb_kernel<<<dim3(256), thr, 0, stream>>>(obs, embed1, emb);
  h1_kernel<<<dim3(256), thr, 0, stream>>>(emb, Wih, bih, bhh, h1);
  trans_kernel<<<dim3(16, 4), thr, 0, stream>>>(We2, we2t, CE, CHID);        // We2T
  x0_kernel<<<dim3(4, 64), thr, 0, stream>>>(h1, we2t, be2, out + O_X);
  trans_kernel<<<dim3(128, 16), thr, 0, stream>>>(Wm1, wm1t, CHID, CA * CE); // Wm1T
  wpm_kernel<<<dim3(256, 4), thr, 0, stream>>>(wm1t, eo, wpm);
  trans_kernel<<<dim3(16, 4), thr, 0, stream>>>(Wm2, wm2t, CE, CHID);        // Wm2T
  tllists_kernel<<<dim3(8), thr, 0, stream>>>(P, cnttl, listtl);
  xstl_kernel<<<dim3(4096), thr, 0, stream>>>(emb, xstl);
  // time-loop model (factorized, f32)
  l1_kernel<<<dim3(32, 8, 8), thr, 0, stream>>>(wpm, xstl, bm1, cnttl, listtl, 256, hbig);
  l2big_kernel<<<dim3(8, 64), thr, 0, stream>>>(hbig, wm2t, parttl);
  ml_kernel<<<dim3(2048), thr, 0, stream>>>(parttl, bm2, emb, out + O_ML);
  // planning loop: 64 chains x 8 eighth-blocks, float4 weight streaming.
  // part_db reuses the parttl region (dead after ml_kernel, stream-ordered).
  plan2_kernel<<<dim3(512), dim3(512), 0, stream>>>(
      wpm, wm2t, bm1, P, Ws, bs, Wc, bc, bm2,
      out + O_X, out + O_SL, out + O_VAL, out + O_PA, flg, part_db);
  el_kernel<<<dim3(2048), thr, 0, stream>>>(emb, out + O_X, Ws, bs, out + O_EL);
}

// Round 14
// 481.468 us; speedup vs baseline: 1.9082x; 1.3518x over previous
//
#include <hip/hip_runtime.h>

// ---------------------------------------------------------------------------
// Problem constants
// ---------------------------------------------------------------------------
constexpr int CT = 32;      // T
constexpr int CN = 64;      // N
constexpr int CE = 256;     // E = DOBS*V
constexpr int CHID = 1024;
constexpr int CA = 32;      // num options
constexpr int CS = 32;      // planning steps
constexpr int CHP = 8;      // planning horizon
constexpr int TN = CT * CN; // 2048

// d_out float offsets (return order: search_logits, planned_actions, X, value,
// model_loss, embed_loss)
constexpr size_t O_SL  = 0;        // 32*64*32 = 65536
constexpr size_t O_PA  = 65536;    // 64*8     = 512
constexpr size_t O_X   = 66048;    // 64*8*256 = 131072
constexpr size_t O_VAL = 197120;   // 32*64    = 2048
constexpr size_t O_ML  = 199168;   // 32*64*256= 524288
constexpr size_t O_EL  = 723456;   // 32*64    = 2048

// ws byte offsets (~100 MB total)
constexpr size_t B_EMB    = 0;                           // 2 MB   [2048][256] f32
constexpr size_t B_H1     = 2u * 1024 * 1024;            // 256 KB [64][1024]
// control block at 3.5 MB (nothing else lives in 3.5..4 MB)
constexpr size_t B_FLG    = 3584u * 1024;                // 64*8*16 ints = 32 KB
constexpr size_t B_CNTTL  = B_FLG + 64 * 1024;           // 32 ints
constexpr size_t B_LISTTL = B_CNTTL + 4 * 1024;          // 32 KB [32][256]
// 32MB+ multi-phase region: We2T (early) -> Wm1T (mid) -> xstl/hbig/parttl/Wm2T
constexpr size_t B_R32    = 4u * 1024 * 1024;
constexpr size_t B_WE2T   = B_R32;                       // 1 MB  (dead after x0)
constexpr size_t B_WM1T   = B_R32;                       // 32 MB (dead after wpm)
constexpr size_t B_XSTL   = B_R32;                       // 4 MB  [2048][512]
constexpr size_t B_HBIG   = B_R32 + 4u * 1024 * 1024;    // 8 MB  [2048][1024]
constexpr size_t B_PARTTL = B_R32 + 12u * 1024 * 1024;   // 16 MB [2048][8][256]
// plan part buffer: PER-STEP slots (33 x 64 x 8 x 256 f32 = 16.5 MB) at +4MB
// abs, overlapping only xstl/hbig/parttl -- all dead after ml_kernel (stream-
// ordered before plan2). Slots never reused -> no overwrite race, ever.
constexpr size_t B_PART3  = B_R32;                       // 16.5 MB [33][64][8][256]
constexpr size_t B_WM2T   = B_R32 + 28u * 1024 * 1024;   // 1 MB  [1024][256] (abs +32MB)
constexpr size_t B_WPM    = B_R32 + 32u * 1024 * 1024;   // 64 MB [32][512][1024]

// LDS scalar-state indices
constexpr int SI_FLAG = 0, SI_I = 1, SI_PUSH = 2, SI_IUP = 3;

__device__ __forceinline__ void fma4(float4& a, float s, const float4& w) {
  a.x = fmaf(s, w.x, a.x); a.y = fmaf(s, w.y, a.y);
  a.z = fmaf(s, w.z, a.z); a.w = fmaf(s, w.w, a.w);
}

// LLC-coherent relaxed accessors (cross-block data; no fences needed: producer
// ordering via __syncthreads' vmcnt drain + explicit waitst before flag post)
__device__ __forceinline__ float gld(const float* p) {
  return __hip_atomic_load(p, __ATOMIC_RELAXED, __HIP_MEMORY_SCOPE_AGENT);
}
__device__ __forceinline__ void gst(float* p, float v) {
  __hip_atomic_store(p, v, __ATOMIC_RELAXED, __HIP_MEMORY_SCOPE_AGENT);
}
__device__ __forceinline__ int gldi(const int* p) {
  return __hip_atomic_load(p, __ATOMIC_RELAXED, __HIP_MEMORY_SCOPE_AGENT);
}
__device__ __forceinline__ void gsti(int* p, int v) {
  __hip_atomic_store(p, v, __ATOMIC_RELAXED, __HIP_MEMORY_SCOPE_AGENT);
}
__device__ __forceinline__ void waitst() {
  asm volatile("s_waitcnt vmcnt(0)" ::: "memory");
}

// ---------------------------------------------------------------------------
// init: zero PA+X span of d_out, per-chain flags, time-loop counters
// ---------------------------------------------------------------------------
__global__ void init_kernel(float* __restrict__ out, int* __restrict__ flg,
                            int* __restrict__ cnt_tl) {
  int idx = blockIdx.x * 256 + threadIdx.x;
  if (idx < 131584) out[O_PA + idx] = 0.f;  // PA (512) + X (131072) contiguous
  if (idx < CN * 8 * 16) flg[idx] = 0;
  if (idx < CA) cnt_tl[idx] = 0;
}

// ---------------------------------------------------------------------------
// emb[t][n][e] = embed1[obs[t][n][e>>4]][e&15]
// ---------------------------------------------------------------------------
__global__ void emb_kernel(const int* __restrict__ obs, const float* __restrict__ embed1,
                           float* __restrict__ emb) {
  int idx = blockIdx.x * 256 + threadIdx.x;
  int b = idx >> 5, k8 = idx & 31;
  int e0 = k8 * 8;
  int d = e0 >> 4;
  int o = obs[b * 16 + d];
  const float* src = embed1 + o * 16 + (e0 & 15);
  float4 v0 = *(const float4*)src;
  float4 v1 = *(const float4*)(src + 4);
  float* dst = emb + (size_t)b * CE + e0;
  *(float4*)dst = v0;
  *(float4*)(dst + 4) = v1;
}

// ---------------------------------------------------------------------------
// One GRU step with h0 = 0 (only Hs[0] used downstream; Whh provably unused)
// ---------------------------------------------------------------------------
__global__ void h1_kernel(const float* __restrict__ emb, const float* __restrict__ Wih,
                          const float* __restrict__ bih, const float* __restrict__ bhh,
                          float* __restrict__ h1) {
  int t = threadIdx.x, bid = blockIdx.x;   // 256 blocks of (64n x 4j)
  int n = t & 63, j = bid * 4 + (t >> 6);
  const float* x = emb + (size_t)n * CE;   // emb[0] rows
  const float* wr = Wih + (size_t)j * CE;
  const float* wz = Wih + (size_t)(CHID + j) * CE;
  const float* wn = Wih + (size_t)(2 * CHID + j) * CE;
  float ar = 0.f, az = 0.f, an = 0.f;
  #pragma unroll 4
  for (int e = 0; e < CE; ++e) {
    float xe = x[e];
    ar += xe * wr[e]; az += xe * wz[e]; an += xe * wn[e];
  }
  ar += bih[j] + bhh[j];
  az += bih[CHID + j] + bhh[CHID + j];
  float r = 1.f / (1.f + expf(-ar));
  float z = 1.f / (1.f + expf(-az));
  float nn = tanhf(an + bih[2 * CHID + j] + r * bhh[2 * CHID + j]);
  h1[(size_t)n * CHID + j] = (1.f - z) * nn;
}

// ---------------------------------------------------------------------------
// Generic 64x64 tiled transpose: in[R][C] -> out[C][R]
// ---------------------------------------------------------------------------
__global__ void trans_kernel(const float* __restrict__ in, float* __restrict__ out,
                             int R, int C) {
  __shared__ float tile[64][65];
  int tj = threadIdx.x & 63, tg = threadIdx.x >> 6;
  int cb = blockIdx.x * 64, rb = blockIdx.y * 64;
  #pragma unroll
  for (int i = 0; i < 16; ++i) {
    int r = tg * 16 + i;
    tile[r][tj] = in[(size_t)(rb + r) * C + cb + tj];
  }
  __syncthreads();
  #pragma unroll
  for (int i = 0; i < 16; ++i) {
    int c2 = tg * 16 + i;
    out[(size_t)(cb + c2) * R + rb + tj] = tile[tj][c2];
  }
}

// ---------------------------------------------------------------------------
// X[:,0] = h1 @ We2^T + be2   (We2T layout [k][e])
// ---------------------------------------------------------------------------
__global__ void x0_kernel(const float* __restrict__ h1, const float* __restrict__ We2T,
                          const float* __restrict__ be2, float* __restrict__ Xout) {
  int et = blockIdx.x, n = blockIdx.y, t = threadIdx.x;
  int el = t & 63, kq = t >> 6;
  __shared__ float hr[1024];
  __shared__ float sred2[4][64];
  for (int idx = t; idx < 1024; idx += 256) hr[idx] = h1[(size_t)n * CHID + idx];
  __syncthreads();
  int e = et * 64 + el;
  float acc = 0.f;
  for (int k = kq * 256; k < kq * 256 + 256; ++k) acc += hr[k] * We2T[(size_t)k * CE + e];
  sred2[kq][el] = acc;
  __syncthreads();
  if (t < 64) {
    float s2 = sred2[0][t] + sred2[1][t] + sred2[2][t] + sred2[3][t] + be2[et * 64 + t];
    Xout[(size_t)(n * CHP) * CE + et * 64 + t] = s2;
  }
}

// ---------------------------------------------------------------------------
// Factorized model weights:
// Wpm[o][e][j]     = sum_a relu( embed_opt[o][a]) * Wm1[j][a*256+e]
// Wpm[o][256+e][j] = sum_a relu(-embed_opt[o][a]) * Wm1[j][a*256+e]
// ---------------------------------------------------------------------------
__global__ void wpm_kernel(const float* __restrict__ Wm1T, const float* __restrict__ eo,
                           float* __restrict__ Wpm) {
  int e = blockIdx.x, jt = blockIdx.y, t = threadIdx.x;
  int j = jt * 256 + t;
  __shared__ float rp[CA * CA], rm[CA * CA];
  for (int idx = t; idx < CA * CA; idx += 256) {
    float v = eo[idx];
    rp[idx] = fmaxf(v, 0.f);
    rm[idx] = fmaxf(-v, 0.f);
  }
  __syncthreads();
  float w[32];
  #pragma unroll
  for (int a = 0; a < 32; ++a) w[a] = Wm1T[(size_t)(a * 256 + e) * CHID + j];
  for (int o = 0; o < 32; ++o) {
    float sp = 0.f, sm = 0.f;
    #pragma unroll
    for (int a = 0; a < 32; ++a) {
      float wa = w[a];
      sp += rp[o * 32 + a] * wa;
      sm += rm[o * 32 + a] * wa;
    }
    Wpm[((size_t)o * 512 + e) * CHID + j] = sp;
    Wpm[((size_t)o * 512 + 256 + e) * CHID + j] = sm;
  }
}

// ---------------------------------------------------------------------------
// Group time-loop rows by option (list order nondeterministic; results aren't)
// ---------------------------------------------------------------------------
__global__ void tllists_kernel(const int* __restrict__ P, int* __restrict__ cnt_tl,
                               int* __restrict__ list_tl) {
  int b = blockIdx.x * 256 + threadIdx.x;
  if (b >= TN) return;
  int a = P[b];
  int slot = atomicAdd(&cnt_tl[a], 1);
  list_tl[a * 256 + slot] = b;
}

// xs_tl[b][k] = relu(+/- prev[b][k&255]),  prev = emb shifted by one t (wrap)
__global__ void xstl_kernel(const float* __restrict__ emb, float* __restrict__ xs) {
  int idx = blockIdx.x * 256 + threadIdx.x;   // < 2048*512
  int b = idx >> 9, k = idx & 511;
  int e = k & 255;
  int bp = (b < CN) ? (b + (CT - 1) * CN) : (b - CN);
  float v = emb[(size_t)bp * CE + e];
  xs[idx] = (k < 256) ? fmaxf(v, 0.f) : fmaxf(-v, 0.f);
}

// ---------------------------------------------------------------------------
// Time-loop factorized model layer 1:
// h[row][j] = relu( sum_{k<512} xs[row][k] * Wpm[o][k][j] + bm1[j] )
// grid (32 o, 8 j-tiles of 128, z row-group start)
// ---------------------------------------------------------------------------
__global__ __launch_bounds__(256) void l1_kernel(
    const float* __restrict__ Wpm, const float* __restrict__ xs,
    const float* __restrict__ bm1, const int* __restrict__ cnt,
    const int* __restrict__ list, int listStride, float* __restrict__ hout) {
  int o = blockIdx.x, jt = blockIdx.y;
  int c = cnt[o];
  if (c <= 0) return;
  __shared__ __align__(16) float sbuf[8192];
  __shared__ int srows[8];
  int t = threadIdx.x;
  int jl = t & 31, kq = t >> 5;
  int jb = jt * 128;
  const float* wb = Wpm + (size_t)o * (512 * CHID) + jb + jl * 4;
  for (int g = blockIdx.z; g * 8 < c; g += gridDim.z) {
    int base = g * 8;
    int nr = min(8, c - base);
    if (t < 8) srows[t] = (t < nr) ? list[o * listStride + base + t] : -1;
    __syncthreads();
    for (int idx = t; idx < 4096; idx += 256) {
      int row = srows[idx >> 9];
      sbuf[idx] = (row >= 0) ? xs[(size_t)row * 512 + (idx & 511)] : 0.f;
    }
    __syncthreads();
    float4 acc[8];
    #pragma unroll
    for (int r = 0; r < 8; ++r) acc[r] = make_float4(0.f, 0.f, 0.f, 0.f);
    int kbase = kq * 64;
    for (int k4 = 0; k4 < 64; k4 += 4) {
      int k = kbase + k4;
      float4 w0 = *(const float4*)(wb + (size_t)(k + 0) * CHID);
      float4 w1 = *(const float4*)(wb + (size_t)(k + 1) * CHID);
      float4 w2 = *(const float4*)(wb + (size_t)(k + 2) * CHID);
      float4 w3 = *(const float4*)(wb + (size_t)(k + 3) * CHID);
      #pragma unroll
      for (int r = 0; r < 8; ++r) {
        float4 xv = *(const float4*)&sbuf[r * 512 + k];
        fma4(acc[r], xv.x, w0); fma4(acc[r], xv.y, w1);
        fma4(acc[r], xv.z, w2); fma4(acc[r], xv.w, w3);
      }
    }
    __syncthreads();
    #pragma unroll
    for (int r = 0; r < 8; ++r)
      *(float4*)&sbuf[(kq * 8 + r) * 128 + jl * 4] = acc[r];
    __syncthreads();
    for (int idx = t; idx < 1024; idx += 256) {
      int r = idx >> 7, jc = idx & 127;
      float s = 0.f;
      #pragma unroll
      for (int q = 0; q < 8; ++q) s += sbuf[(q * 8 + r) * 128 + jc];
      int row = srows[r];
      if (row >= 0)
        hout[(size_t)row * CHID + jb + jc] = fmaxf(s + bm1[jb + jc], 0.f);
    }
    __syncthreads();
  }
}

// ---------------------------------------------------------------------------
// Time-loop layer 2 partials: part[b][kq][e], 8 k-slices of 128
// grid (8 kq, 64 row-groups of 32), 256 thr (= e)
// ---------------------------------------------------------------------------
__global__ __launch_bounds__(256) void l2big_kernel(const float* __restrict__ h,
    const float* __restrict__ Wm2T, float* __restrict__ part) {
  int kq = blockIdx.x, rg = blockIdx.y, t = threadIdx.x;
  int rb = rg * 32, kb = kq * 128;
  __shared__ __align__(16) float hl[4096];
  for (int idx = t; idx < 4096; idx += 256)
    hl[idx] = h[(size_t)(rb + (idx >> 7)) * CHID + kb + (idx & 127)];
  __syncthreads();
  float acc[32];
  #pragma unroll
  for (int r = 0; r < 32; ++r) acc[r] = 0.f;
  for (int kk = 0; kk < 128; kk += 4) {
    float w0 = Wm2T[(size_t)(kb + kk + 0) * CE + t];
    float w1 = Wm2T[(size_t)(kb + kk + 1) * CE + t];
    float w2 = Wm2T[(size_t)(kb + kk + 2) * CE + t];
    float w3 = Wm2T[(size_t)(kb + kk + 3) * CE + t];
    #pragma unroll
    for (int r = 0; r < 32; ++r) {
      float4 hv = *(const float4*)&hl[r * 128 + kk];
      acc[r] += hv.x * w0 + hv.y * w1 + hv.z * w2 + hv.w * w3;
    }
  }
  #pragma unroll
  for (int r = 0; r < 32; ++r)
    part[((size_t)(rb + r) * 8 + kq) * CE + t] = acc[r];
}

// model_loss = (sum(partials)+bm2 - emb)^2
__global__ void ml_kernel(const float* __restrict__ part, const float* __restrict__ bm2,
                          const float* __restrict__ emb, float* __restrict__ ML) {
  int idx = blockIdx.x * 256 + threadIdx.x;   // < 2048*256
  int b = idx >> 8, e = idx & 255;
  float outv = bm2[e];
  #pragma unroll
  for (int q = 0; q < 8; ++q) outv += part[((size_t)b * 8 + q) * CE + e];
  float d = outv - emb[idx];
  ML[idx] = d * d;
}

// ---------------------------------------------------------------------------
// plan2: 512 blocks = 64 independent chains x 8 j-eighth blocks, 512 thr.
// Compaction: xs = [relu(x); relu(-x)] has exactly one nonzero per pair ->
// gather 256 Wpm rows via skidx (2x less traffic + FLOPs). Parts in PER-STEP
// slots (never reused -> no overwrite race).
// ROUND-14 PROTOCOL FIX: flags are UNCONDITIONAL -- every replica posts
// flg=s+1 every iteration (push or pop), and every epilogue waits flg>=s.
// A flag-post gap or replica divergence can no longer deadlock: worst case
// is a stale part read -> visible absmax failure (diagnostic), not a hang.
// ---------------------------------------------------------------------------
__global__ __launch_bounds__(512) void plan2_kernel(
    const float* __restrict__ Wpm, const float* __restrict__ Wm2T,
    const float* __restrict__ bm1g, const int* __restrict__ P,
    const float* __restrict__ Wsg, const float* __restrict__ bsg,
    const float* __restrict__ Wcg, const float* __restrict__ bcg,
    const float* __restrict__ bm2, float* __restrict__ Xout,
    float* __restrict__ SLout, float* __restrict__ VALout,
    float* __restrict__ PAout, int* __restrict__ flg,
    float* __restrict__ part_db) {
  __shared__ float Xlds[CHP * CE];      // replicated plan buffer (8 KB)
  __shared__ int   skidx[256];          // compacted Wpm row index per e
  __shared__ float sxv[256];            // |x_e|
  __shared__ float sh[128];             // h eighth
  __shared__ __align__(16) float red[2048];  // 16-way partials / l2 halves
  __shared__ float sx[256];
  __shared__ float sred[8];
  __shared__ float svals[32];
  __shared__ float sxtra[2];
  __shared__ int   sint[4];
  __shared__ float logits_s[32];

  int bid = blockIdx.x, t = threadIdx.x;
  int n = bid >> 3, q = bid & 7;
  int jb = q * 128;
  int c2 = t >> 3, g = t & 7;
  int jq = t & 31, kg = t >> 5;         // l1: jq = float4 j-lane, kg = row-group
  int e2 = t & 255, hf = t >> 8;        // l2: e lane, kl half

  // prologue: replicated chain state
  for (int idx = t; idx < CHP * CE; idx += 512)
    Xlds[idx] = Xout[(size_t)n * (CHP * CE) + idx];
  if (t < 32) logits_s[t] = 0.f;
  if (t < 4) sint[t] = 0;
  __syncthreads();

  for (int s = 0; s <= CS; ++s) {
    // read-only prefetch (L2-warm; hidden under the flag wait)
    float wsv = 0.f, bm2v = 0.f, bcv = 0.f, bsv = bsg[0];
    float wcv[32];
    if (t < 256) {
      wsv = Wsg[t]; bm2v = bm2[t];
      #pragma unroll
      for (int i = 0; i < 32; ++i) wcv[i] = Wcg[c2 * CE + g * 32 + i];
    }
    if (t < CA) bcv = bcg[t];

    // ---- epilogue of step s-1 (UNCONDITIONAL replica lockstep wait) ----
    if (s > 0) {
      if (t < 8) {
        const int* fp = &flg[(n * 8 + t) * 16];
        while (gldi(fp) < s) __builtin_amdgcn_s_sleep(1);
      }
      __syncthreads();
      if (sint[SI_PUSH]) {
        int Iup = sint[SI_IUP];
        if (t < 256) {
          float outv = bm2v;
          #pragma unroll
          for (int qq = 0; qq < 8; ++qq)
            outv += gld(&part_db[(((size_t)(s - 1) * CN + n) * 8 + qq) * CE + t]);
          Xlds[Iup * CE + t] = outv;
          if (q == 0) Xout[((size_t)(n * CHP) + Iup) * CE + t] = outv;
          sx[t] = outv;
        }
        if (t == 0) sint[SI_I] = Iup;
      } else {
        int I0 = sint[SI_I];
        int Inew = (I0 - 1 > 0) ? I0 - 1 : 0;
        if (t < 256) sx[t] = Xlds[Inew * CE + t];
        if (t == 0) sint[SI_I] = Inew;
      }
      if (s == CS) break;  // final epilogue only (uniform)
    } else {
      if (t < 256) sx[t] = Xlds[t];
      if (t == 0) sint[SI_I] = 0;
    }
    __syncthreads();
    int I = sint[SI_I];

    // ---- decision (replicated identically in all 8 q-blocks) ----
    if (t < 256) {
      float xv = sx[t];
      float xa = fmaxf(xv, 0.f);
      skidx[t] = (xv > 0.f) ? t : 256 + t;
      sxv[t] = fabsf(xv);
      float v = xa * wsv;
      #pragma unroll
      for (int off = 32; off > 0; off >>= 1) v += __shfl_down(v, off, 64);
      if ((t & 63) == 0) sred[t >> 6] = v;
      float pv = 0.f;
      #pragma unroll 4
      for (int i = 0; i < 32; ++i)
        pv += fmaxf(sx[g * 32 + i], 0.f) * wcv[i];
      pv += __shfl_down(pv, 4, 8);
      pv += __shfl_down(pv, 2, 8);
      pv += __shfl_down(pv, 1, 8);
      if (g == 0) svals[c2] = pv + bcv;
    }
    __syncthreads();
    if (t == 0) {
      sxtra[0] = sred[0] + sred[1] + sred[2] + sred[3] + bsv;
      sint[SI_FLAG] = 1;
    }
    __syncthreads();
    if (t < CA && logits_s[t] != 0.f) sint[SI_FLAG] = 0;
    __syncthreads();
    int a = P[s * CN + n];
    if (t < CA) {
      float v = svals[t];
      float slv = sint[SI_FLAG] ? sxtra[0] * v : logits_s[t];
      if (q == 0) SLout[(size_t)(s * CN + n) * CA + t] = slv;
      logits_s[t] = slv - (t == a ? 1e8f : 0.f);
      if (t == a) {
        if (q == 0) { VALout[s * CN + n] = slv; PAout[n * CHP + I] = (float)a; }
        sint[SI_PUSH] = (v > 0.f) ? 1 : 0;
        sint[SI_IUP] = (I + 1 < CHP - 1) ? I + 1 : CHP - 1;
      }
    }
    __syncthreads();

    // ---- model eval (push only): j-eighth, COMPACTED 256-row W stream ----
    if (sint[SI_PUSH]) {
      // l1: thread (kg, jq): float4 over j = jb+jq*4, rows e in [kg*16, +16)
      const float* wbase = Wpm + (size_t)a * (512 * CHID) + jb + jq * 4;
      float4 acc; acc.x = acc.y = acc.z = acc.w = 0.f;
      #pragma unroll 8
      for (int ii = 0; ii < 16; ++ii) {
        int e = kg * 16 + ii;
        float4 wv = *(const float4*)(wbase + (size_t)skidx[e] * CHID);
        fma4(acc, sxv[e], wv);
      }
      *(float4*)&red[kg * 128 + jq * 4] = acc;
      __syncthreads();
      if (t < 128) {
        float s1 = 0.f;
        #pragma unroll
        for (int gg = 0; gg < 16; ++gg) s1 += red[gg * 128 + t];
        sh[t] = fmaxf(s1 + bm1g[jb + t], 0.f);
      }
      __syncthreads();
      // l2: part_q[e] = sum_{kl<128} sh[kl] * Wm2T[(jb+kl)*CE+e], 2x64 split
      {
        const float* w2 = Wm2T + (size_t)(jb + hf * 64) * CE + e2;
        float a2 = 0.f;
        #pragma unroll 8
        for (int kl = 0; kl < 64; ++kl)
          a2 = fmaf(sh[hf * 64 + kl], w2[(size_t)kl * CE], a2);
        red[hf * 256 + e2] = a2;
      }
      __syncthreads();
      if (t < 256) {
        gst(&part_db[(((size_t)s * CN + n) * 8 + q) * CE + t],
            red[t] + red[256 + t]);
      }
    }
    __syncthreads();              // drains all stores (vmcnt before s_barrier)
    if (t == 0) {
      waitst();
      gsti(&flg[(n * 8 + q) * 16], s + 1);   // UNCONDITIONAL post
    }
    __syncthreads();
  }
}

// ---------------------------------------------------------------------------
// embed_loss
// ---------------------------------------------------------------------------
__global__ void el_kernel(const float* __restrict__ emb, const float* __restrict__ Xout,
                          const float* __restrict__ Ws, const float* __restrict__ bsp,
                          float* __restrict__ EL) {
  int tn = blockIdx.x;
  int n = tn & 63;
  int t = threadIdx.x, h = t >> 5, l = t & 31;
  const float* er = emb + (size_t)tn * CE;
  const float* xr = Xout + ((size_t)(n * CHP) + h) * CE;
  float pd = 0.f, px = 0.f, pe = 0.f, ps = 0.f;
  #pragma unroll
  for (int i = 0; i < 8; ++i) {
    int e = l * 8 + i;
    float ev = er[e], xv2 = xr[e];
    pd += ev * xv2; px += xv2 * xv2; pe += ev * ev; ps += fmaxf(ev, 0.f) * Ws[e];
  }
  #pragma unroll
  for (int off = 16; off > 0; off >>= 1) {
    pd += __shfl_down(pd, off, 32);
    px += __shfl_down(px, off, 32);
    pe += __shfl_down(pe, off, 32);
    ps += __shfl_down(ps, off, 32);
  }
  __shared__ float sdot[8], snx[8];
  __shared__ float sne, ssh;
  if (l == 0) {
    sdot[h] = pd;
    snx[h] = sqrtf(px);
    if (h == 0) { sne = sqrtf(pe); ssh = ps + bsp[0]; }
  }
  __syncthreads();
  if (t == 0) {
    const float eps = 1e-8f;
    float y[8];
    float m = -1e30f;
    #pragma unroll
    for (int hh = 0; hh < 8; ++hh) {
      float cs = sdot[hh] / ((sne + eps) * (snx[hh] + eps));
      y[hh] = ssh * cs;
      m = fmaxf(m, y[hh]);
    }
    float sum = 0.f;
    #pragma unroll
    for (int hh = 0; hh < 8; ++hh) sum += expf(y[hh] - m);
    float lse = logf(sum);
    float el = 0.f;
    #pragma unroll
    for (int hh = 0; hh < 8; ++hh) {
      float lp = y[hh] - m - lse;
      el += expf(lp) * lp;
    }
    EL[tn] = el;
  }
}

// ---------------------------------------------------------------------------
extern "C" void kernel_launch(void* const* d_in, const int* in_sizes, int n_in,
                              void* d_out, int out_size, void* d_ws, size_t ws_size,
                              hipStream_t stream) {
  (void)in_sizes; (void)n_in; (void)out_size; (void)ws_size;
  const int*   obs    = (const int*)d_in[0];
  const int*   P      = (const int*)d_in[1];
  const float* embed1 = (const float*)d_in[2];
  const float* Wih    = (const float*)d_in[3];
  // d_in[4] = Whh: provably unused (h0 = 0 and only Hs[0] is consumed)
  const float* bih    = (const float*)d_in[5];
  const float* bhh    = (const float*)d_in[6];
  const float* We2    = (const float*)d_in[7];
  const float* be2    = (const float*)d_in[8];
  const float* Ws     = (const float*)d_in[9];
  const float* bs     = (const float*)d_in[10];
  const float* Wc     = (const float*)d_in[11];
  const float* bc     = (const float*)d_in[12];
  const float* Wm1    = (const float*)d_in[13];
  const float* bm1    = (const float*)d_in[14];
  const float* Wm2    = (const float*)d_in[15];
  const float* bm2    = (const float*)d_in[16];
  const float* eo     = (const float*)d_in[17];
  float* out = (float*)d_out;
  char*  ws  = (char*)d_ws;

  float* emb    = (float*)(ws + B_EMB);
  float* h1     = (float*)(ws + B_H1);
  float* part_db= (float*)(ws + B_PART3);
  int*   flg    = (int*)(ws + B_FLG);
  int*   cnttl  = (int*)(ws + B_CNTTL);
  int*   listtl = (int*)(ws + B_LISTTL);
  float* we2t   = (float*)(ws + B_WE2T);
  float* wm1t   = (float*)(ws + B_WM1T);
  float* xstl   = (float*)(ws + B_XSTL);
  float* hbig   = (float*)(ws + B_HBIG);
  float* parttl = (float*)(ws + B_PARTTL);
  float* wm2t   = (float*)(ws + B_WM2T);
  float* wpm    = (float*)(ws + B_WPM);

  dim3 thr(256);
  init_kernel<<<dim3(514), thr, 0, stream>>>(out, flg, cnttl);
  emb_kernel<<<dim3(256), thr, 0, stream>>>(obs, embed1, emb);
  h1_kernel<<<dim3(256), thr, 0, stream>>>(emb, Wih, bih, bhh, h1);
  trans_kernel<<<dim3(16, 4), thr, 0, stream>>>(We2, we2t, CE, CHID);        // We2T
  x0_kernel<<<dim3(4, 64), thr, 0, stream>>>(h1, we2t, be2, out + O_X);
  trans_kernel<<<dim3(128, 16), thr, 0, stream>>>(Wm1, wm1t, CHID, CA * CE); // Wm1T
  wpm_kernel<<<dim3(256, 4), thr, 0, stream>>>(wm1t, eo, wpm);
  trans_kernel<<<dim3(16, 4), thr, 0, stream>>>(Wm2, wm2t, CE, CHID);        // Wm2T
  tllists_kernel<<<dim3(8), thr, 0, stream>>>(P, cnttl, listtl);
  xstl_kernel<<<dim3(4096), thr, 0, stream>>>(emb, xstl);
  // time-loop model (factorized, f32)
  l1_kernel<<<dim3(32, 8, 8), thr, 0, stream>>>(wpm, xstl, bm1, cnttl, listtl, 256, hbig);
  l2big_kernel<<<dim3(8, 64), thr, 0, stream>>>(hbig, wm2t, parttl);
  ml_kernel<<<dim3(2048), thr, 0, stream>>>(parttl, bm2, emb, out + O_ML);
  // planning loop: 64 chains x 8 eighth-blocks, compacted W stream, per-step
  // part slots, UNCONDITIONAL flag protocol (hang-proof)
  plan2_kernel<<<dim3(512), dim3(512), 0, stream>>>(
      wpm, wm2t, bm1, P, Ws, bs, Wc, bc, bm2,
      out + O_X, out + O_SL, out + O_VAL, out + O_PA, flg, part_db);
  el_kernel<<<dim3(2048), thr, 0, stream>>>(emb, out + O_X, Ws, bs, out + O_EL);
}